// Round 10
// baseline (241.668 us; speedup 1.0000x reference)
//
#include <hip/hip_runtime.h>

#define SS 4096
#define DD 64
#define NH 16
#define QB 128
#define NQB (SS / QB)      // 32
#define KVT 64
#define NKV (SS / KVT)     // 64
#define TILE_BYTES 8192    // 64 x 64 bf16

// chunking: q-block p has W=2p+2 tiles, split into n=(p>>2)+1 balanced chunks
// (target ~8 tiles). 144 chunks/head, 2304 blocks total.
#define CHUNKS_PER_H 144
#define ACCW_PER_H   112   // chunks with ci>=1
#define LM_PLANE     (16 * CHUNKS_PER_H * 128)   // 294912

typedef float  fx4    __attribute__((ext_vector_type(4)));
typedef __bf16 bf16x8 __attribute__((ext_vector_type(8)));
typedef short  sx4    __attribute__((ext_vector_type(4)));
typedef unsigned short usx4 __attribute__((ext_vector_type(4)));

typedef __attribute__((address_space(1))) const unsigned int GU32;
typedef __attribute__((address_space(3))) unsigned int       LU32;

__device__ __forceinline__ void gload16(const void* g, void* l) {
    __builtin_amdgcn_global_load_lds((GU32*)g, (LU32*)l, 16, 0, 0);
}

__device__ __forceinline__ float fast_exp2(float x) {
    return __builtin_amdgcn_exp2f(x);   // v_exp_f32: 2^x
}

// ---------------- pre-pass: f32 K/V -> bf16 tile images ----------------
// K image: swizzled (for LDS ds_read); V image: PLAIN V^T rows (global reads).
__global__ __launch_bounds__(256)
void prep_kernel(const float* __restrict__ Kg, const float* __restrict__ Vg,
                 char* __restrict__ Kimg, char* __restrict__ Vimg)
{
    __shared__ __bf16 lv[64][72];
    const int tid = threadIdx.x;
    const int h = (int)blockIdx.x >> 6;
    const int t = (int)blockIdx.x & 63;
    const int r = tid >> 2;                       // 0..63
    const size_t rowbase = ((size_t)h * SS + (size_t)t * KVT) * DD;

    // ---- K (swizzled 16B chunks) ----
    {
        char* kdst = Kimg + (size_t)(h * NKV + t) * TILE_BYTES;
        const float* src = Kg + rowbase + (size_t)r * DD;
#pragma unroll
        for (int cc = 0; cc < 2; ++cc) {
            const int c = (tid & 3) * 2 + cc;     // 0..7
            fx4 f0 = *(const fx4*)(src + c * 8);
            fx4 f1 = *(const fx4*)(src + c * 8 + 4);
            bf16x8 b;
#pragma unroll
            for (int j = 0; j < 4; ++j) { b[j] = (__bf16)f0[j]; b[4 + j] = (__bf16)f1[j]; }
            *(bf16x8*)(kdst + r * 128 + ((c ^ (r & 7)) << 4)) = b;
        }
    }

    // ---- V: load tile to LDS (row-major), then write transposed, plain ----
    {
        const float* src = Vg + rowbase + (size_t)r * DD + (tid & 3) * 16;
#pragma unroll
        for (int qq = 0; qq < 4; ++qq) {
            fx4 f = *(const fx4*)(src + qq * 4);
#pragma unroll
            for (int j = 0; j < 4; ++j) lv[r][(tid & 3) * 16 + qq * 4 + j] = (__bf16)f[j];
        }
    }
    __syncthreads();
    {
        char* vdst = Vimg + (size_t)(h * NKV + t) * TILE_BYTES;
        const int d = r;                          // VT row
#pragma unroll
        for (int cc = 0; cc < 2; ++cc) {
            const int c = (tid & 3) * 2 + cc;     // k-chunk 0..7
            bf16x8 b;
#pragma unroll
            for (int j = 0; j < 8; ++j) b[j] = lv[c * 8 + j][d];
            *(bf16x8*)(vdst + d * 128 + (c << 4)) = b;
        }
    }
}

// ---------------- main kernel: K via LDS, V direct from L2, KV chunks ----------------
__global__ __launch_bounds__(256, 4)
void attn_fwd(const float* __restrict__ Qg, const char* __restrict__ Kimg,
              const char* __restrict__ Vimg, float* __restrict__ Og,
              unsigned short* __restrict__ accW, float* __restrict__ lmW)
{
    __shared__ __align__(16) char lK[2][TILE_BYTES];   // 16 KB total

    const int tid  = threadIdx.x;
    const int wid  = tid >> 6;                    // 0..3
    const int lane = tid & 63;
    const int lr   = lane & 15;
    const int g    = lane >> 4;

    // ---- chunk decode (all scalar) ----
    const int b = (int)blockIdx.x;                // 0..2303
    const int h = b / CHUNKS_PER_H;
    int r_ = (CHUNKS_PER_H - 1) - (b - h * CHUNKS_PER_H);   // logical cid, reversed
    const int cid = r_;
    int m = 0;
#pragma unroll
    for (int i = 0; i < 7; ++i) {                 // group m starts at 2m(m+1), width 4(m+1)
        if (r_ >= 4 * (i + 1)) { r_ -= 4 * (i + 1); m = i + 1; }
    }
    int p4 = 0;
#pragma unroll
    for (int i = 0; i < 3; ++i) {
        if (r_ >= m + 1) { r_ -= (m + 1); ++p4; }
    }
    const int p  = 4 * m + p4;
    const int ci = r_;
    const int n  = m + 1;
    const int W  = 2 * p + 2;
    const int t0 = (ci * W) / n;
    const int t1 = ((ci + 1) * W) / n;

    const int q0 = p * QB + wid * 32;             // wave owns 32 q rows (2 subtiles)

    const float* Qh = Qg + (size_t)h * SS * DD;
    float*       Oh = Og + (size_t)h * SS * DD;
    const char*  Kh = Kimg + (size_t)(h * NKV) * TILE_BYTES;
    const char*  Vh = Vimg + (size_t)(h * NKV) * TILE_BYTES;

    const float QSCALE = 0.125f * 1.44269504088896f;   // 1/sqrt(64) * log2(e)

    // ---- hoisted LDS byte offsets (loop-invariant) ----
    int koff[4][2];
#pragma unroll
    for (int ks = 0; ks < 4; ++ks) {
        const int row = ks * 16 + lr;
        koff[ks][0] = row * 128 + (((g    ) ^ (lr & 7)) << 4);
        koff[ks][1] = row * 128 + (((g ^ 4) ^ (lr & 7)) << 4);
    }
    const int vbase = lr * 128 + g * 8;           // + d0*2048 + ks*32 immediates

    // Q fragments (held all kernel)
    bf16x8 qa[2][2];
#pragma unroll
    for (int u = 0; u < 2; ++u) {
        const int qrow = q0 + 16 * u + lr;
#pragma unroll
        for (int h2 = 0; h2 < 2; ++h2) {
            const float* src = Qh + (size_t)qrow * DD + h2 * 32 + g * 8;
            fx4 f0 = *(const fx4*)(src);
            fx4 f1 = *(const fx4*)(src + 4);
            bf16x8 tq;
#pragma unroll
            for (int jj = 0; jj < 4; ++jj) {
                tq[jj]     = (__bf16)(f0[jj] * QSCALE);
                tq[jj + 4] = (__bf16)(f1[jj] * QSCALE);
            }
            qa[u][h2] = tq;
        }
    }

    fx4 acc[2][4];
#pragma unroll
    for (int u = 0; u < 2; ++u)
#pragma unroll
        for (int d0 = 0; d0 < 4; ++d0) acc[u][d0] = (fx4){0.f, 0.f, 0.f, 0.f};
    float m_run = -1e30f;           // wave-uniform running max (log2 units)
    float l_run[2] = {0.f, 0.f};    // lane-local partial row sums

    // staging: 4 waves share the 8KB K tile (2KB = 2 x 1KB gload16 per wave)
#define STAGE(buf, tt)                                                          \
    do {                                                                        \
        const char* src_ = Kh + (size_t)(tt) * TILE_BYTES + wid * 2048          \
                           + lane * 16;                                         \
        char* dst_ = &lK[buf][wid * 2048];                                      \
        gload16(src_,        dst_);                                             \
        gload16(src_ + 1024, dst_ + 1024);                                      \
    } while (0)

    STAGE(0, t0);
    __syncthreads();

    int cur = 0;
    for (int t = t0; t < t1; ++t) {
        if (t + 1 < t1) STAGE(cur ^ 1, t + 1);   // prefetch next K tile

        // ---- QK^T (swapped: A=K tile rows, B=Q) ----
        float s[2][4][4];
        const char* kb = &lK[cur][0];
        __builtin_amdgcn_s_setprio(1);
#pragma unroll
        for (int ks = 0; ks < 4; ++ks) {
            const bf16x8 ka0 = *(const bf16x8*)(kb + koff[ks][0]);
            const bf16x8 ka1 = *(const bf16x8*)(kb + koff[ks][1]);
#pragma unroll
            for (int u = 0; u < 2; ++u) {
                fx4 st = (fx4){0.f, 0.f, 0.f, 0.f};
                st = __builtin_amdgcn_mfma_f32_16x16x32_bf16(ka0, qa[u][0], st, 0, 0, 0);
                st = __builtin_amdgcn_mfma_f32_16x16x32_bf16(ka1, qa[u][1], st, 0, 0, 0);
#pragma unroll
                for (int r = 0; r < 4; ++r) s[u][ks][r] = st[r];
            }
        }
        __builtin_amdgcn_s_setprio(0);

        // ---- V fragments direct from L2 (plain V^T image); softmax hides latency ----
        sx4 vbr[4][4];
        {
            const char* vt = Vh + (size_t)t * TILE_BYTES + vbase;
#pragma unroll
            for (int ks = 0; ks < 4; ++ks)
#pragma unroll
                for (int d0 = 0; d0 < 4; ++d0)
                    vbr[ks][d0] = *(const sx4*)(vt + d0 * 2048 + ks * 32);
        }

        // ---- causal mask (tile crosses diagonal iff t >= 2p) ----
        if (t >= 2 * p) {
            const int kv0 = t * KVT;
#pragma unroll
            for (int u = 0; u < 2; ++u) {
                const int qrow = q0 + 16 * u + lr;
#pragma unroll
                for (int ks = 0; ks < 4; ++ks)
#pragma unroll
                    for (int r = 0; r < 4; ++r) {
                        const int kvi = kv0 + ks * 16 + 4 * g + r;
                        if (kvi > qrow) s[u][ks][r] = -1e30f;
                    }
            }
        }

        // ---- softmax: max3-shaped reduce, rare wave-uniform rescale ----
        float m4[2][4];
#pragma unroll
        for (int u = 0; u < 2; ++u)
#pragma unroll
            for (int ks = 0; ks < 4; ++ks)
                m4[u][ks] = fmaxf(fmaxf(s[u][ks][0], s[u][ks][1]),
                                  fmaxf(s[u][ks][2], s[u][ks][3]));
        const float ta = fmaxf(fmaxf(m4[0][0], m4[0][1]), m4[0][2]);
        const float tb = fmaxf(fmaxf(m4[0][3], m4[1][0]), m4[1][1]);
        const float tc = fmaxf(fmaxf(m4[1][2], m4[1][3]), ta);
        const float tm = fmaxf(tb, tc);

        if (__any(tm > m_run + 8.0f)) {           // rare after first tile
            float wm = tm;
            wm = fmaxf(wm, __shfl_xor(wm, 1));
            wm = fmaxf(wm, __shfl_xor(wm, 2));
            wm = fmaxf(wm, __shfl_xor(wm, 4));
            wm = fmaxf(wm, __shfl_xor(wm, 8));
            wm = fmaxf(wm, __shfl_xor(wm, 16));
            wm = fmaxf(wm, __shfl_xor(wm, 32));   // wave max, uniform
            const float alpha = fast_exp2(m_run - wm);
            m_run = wm;
            l_run[0] *= alpha; l_run[1] *= alpha;
#pragma unroll
            for (int u = 0; u < 2; ++u)
#pragma unroll
                for (int d0 = 0; d0 < 4; ++d0) {
                    fx4 a = acc[u][d0];
                    a[0] *= alpha; a[1] *= alpha; a[2] *= alpha; a[3] *= alpha;
                    acc[u][d0] = a;
                }
        }

        sx4 pa[2][4];
#pragma unroll
        for (int u = 0; u < 2; ++u) {
#pragma unroll
            for (int ks = 0; ks < 4; ++ks)
#pragma unroll
                for (int r = 0; r < 4; ++r)
                    s[u][ks][r] = fast_exp2(s[u][ks][r] - m_run);   // in-place P
            const float u0 = (s[u][0][0] + s[u][0][1]) + (s[u][0][2] + s[u][0][3]);
            const float u1 = (s[u][1][0] + s[u][1][1]) + (s[u][1][2] + s[u][1][3]);
            const float u2 = (s[u][2][0] + s[u][2][1]) + (s[u][2][2] + s[u][2][3]);
            const float u3 = (s[u][3][0] + s[u][3][1]) + (s[u][3][2] + s[u][3][3]);
            l_run[u] += (u0 + u1) + (u2 + u3);
#pragma unroll
            for (int ks = 0; ks < 4; ++ks) {
                sx4 t4;
#pragma unroll
                for (int jj = 0; jj < 4; ++jj) {
                    const __bf16 pb = (__bf16)s[u][ks][jj];
                    t4[jj] = __builtin_bit_cast(short, pb);
                }
                pa[u][ks] = t4;
            }
        }

        // ---- PV: P already in MFMA A-layout; V fragments in registers ----
        __builtin_amdgcn_s_setprio(1);
#pragma unroll
        for (int ks = 0; ks < 4; ++ks) {
#pragma unroll
            for (int d0 = 0; d0 < 4; ++d0) {
                acc[0][d0] = __builtin_amdgcn_mfma_f32_16x16x16bf16_1k(pa[0][ks], vbr[ks][d0], acc[0][d0], 0, 0, 0);
                acc[1][d0] = __builtin_amdgcn_mfma_f32_16x16x16bf16_1k(pa[1][ks], vbr[ks][d0], acc[1][d0], 0, 0, 0);
            }
        }
        __builtin_amdgcn_s_setprio(0);

        if (t + 1 < t1) __syncthreads();          // K buffer swap safe
        cur ^= 1;
    }

    // ---- epilogue: reduce l across g, write partial + lm ----
    float ls0 = l_run[0];
    ls0 += __shfl_xor(ls0, 16);
    ls0 += __shfl_xor(ls0, 32);
    float ls1 = l_run[1];
    ls1 += __shfl_xor(ls1, 16);
    ls1 += __shfl_xor(ls1, 32);

    const int rowb = (h * CHUNKS_PER_H + cid) * 128 + wid * 32 + lr;
    if (lane < 16) {
        lmW[rowb]                  = m_run;
        lmW[rowb + 16]             = m_run;
        lmW[LM_PLANE + rowb]       = ls0;
        lmW[LM_PLANE + rowb + 16]  = ls1;
    }

    if (ci == 0) {                   // raw f32 acc -> Og
#pragma unroll
        for (int u = 0; u < 2; ++u)
#pragma unroll
            for (int d0 = 0; d0 < 4; ++d0)
#pragma unroll
                for (int r = 0; r < 4; ++r)
                    Oh[(size_t)(q0 + 16 * u + 4 * g + r) * DD + d0 * 16 + lr] = acc[u][d0][r];
    } else {                         // bf16 acc -> accW (dense idx = cid - p - 1)
        const size_t ab = ((size_t)(h * ACCW_PER_H) + (cid - p - 1)) * 8192
                        + (size_t)(wid * 32) * 64;
#pragma unroll
        for (int u = 0; u < 2; ++u)
#pragma unroll
            for (int d0 = 0; d0 < 4; ++d0)
#pragma unroll
                for (int r = 0; r < 4; ++r) {
                    const __bf16 pb = (__bf16)acc[u][d0][r];
                    accW[ab + (size_t)(16 * u + 4 * g + r) * 64 + d0 * 16 + lr] =
                        __builtin_bit_cast(unsigned short, pb);
                }
    }
#undef STAGE
}

// ---------------- combine: branchless unrolled 8-way merge ----------------
__global__ __launch_bounds__(256)
void combine_kernel(float* __restrict__ Og, const unsigned short* __restrict__ accW,
                    const float* __restrict__ lmW)
{
    const int blk = (int)blockIdx.x;      // 0..4095
    const int rg = blk & 7;
    const int p  = (blk >> 3) & 31;
    const int h  = blk >> 8;

    const int m = p >> 2, n = m + 1;
    const int cid0 = 2 * m * (m + 1) + (p & 3) * n;
    const int lmB  = (h * CHUNKS_PER_H + cid0) * 128;
    const size_t obase = ((size_t)h * SS + (size_t)p * QB) * DD;
    const size_t ab0   = ((size_t)(h * ACCW_PER_H) + (cid0 - p)) * 8192;  // chunk ci=1

    const int row = rg * 16 + ((int)threadIdx.x >> 4);     // 0..127
    const int c4  = ((int)threadIdx.x & 15) * 4;           // 0..60

    // ---- per-row stats: 8-wide, clamped loads, padding weight-zeroed ----
    float mi[8], li[8];
#pragma unroll
    for (int i = 0; i < 8; ++i) {
        const int ic = (i < n) ? i : 0;
        mi[i] = lmW[lmB + ic * 128 + row];
        li[i] = lmW[LM_PLANE + lmB + ic * 128 + row];
    }
#pragma unroll
    for (int i = 0; i < 8; ++i) {
        if (i >= n) { mi[i] = -3.0e38f; li[i] = 0.f; }
    }
    const float mm = fmaxf(fmaxf(fmaxf(mi[0], mi[1]), fmaxf(mi[2], mi[3])),
                           fmaxf(fmaxf(mi[4], mi[5]), fmaxf(mi[6], mi[7])));
    float w[8];
    float den = 0.f;
#pragma unroll
    for (int i = 0; i < 8; ++i) {
        w[i] = fast_exp2(mi[i] - mm);     // exp2(-huge) = 0 for padding
        den += w[i] * li[i];
    }

    // ---- element merge: chunk0 (f32, in Og) + chunks 1..n-1 (bf16, accW) ----
    const size_t oi = obase + (size_t)row * DD + c4;
    fx4 val = *(const fx4*)(&Og[oi]);
    val[0] *= w[0]; val[1] *= w[0]; val[2] *= w[0]; val[3] *= w[0];

#pragma unroll
    for (int i = 1; i < 8; ++i) {
        const int ai = (i < n) ? (i - 1) : 0;              // clamped, always valid
        const usx4 ub = *(const usx4*)(&accW[ab0 + (size_t)ai * 8192 + row * 64 + c4]);
#pragma unroll
        for (int j = 0; j < 4; ++j) {
            const unsigned int bits = ((unsigned int)ub[j]) << 16;
            val[j] += w[i] * __builtin_bit_cast(float, bits);
        }
    }

    const float rinv = 1.f / den;
    val[0] *= rinv; val[1] *= rinv; val[2] *= rinv; val[3] *= rinv;
    *(fx4*)(&Og[oi]) = val;
}

extern "C" void kernel_launch(void* const* d_in, const int* in_sizes, int n_in,
                              void* d_out, int out_size, void* d_ws, size_t ws_size,
                              hipStream_t stream)
{
    (void)in_sizes; (void)n_in; (void)out_size; (void)ws_size;
    const float* q = (const float*)d_in[0];
    const float* k = (const float*)d_in[1];
    const float* v = (const float*)d_in[2];
    float*       o = (float*)d_out;

    char* ws = (char*)d_ws;
    char*           Kimg = ws;                                        // 8 MB
    char*           Vimg = ws + ((size_t)1 << 23);                    // 8 MB
    unsigned short* accW = (unsigned short*)(ws + ((size_t)2 << 23)); // 29.4 MB bf16 partials
    float*          lmW  = (float*)(ws + ((size_t)2 << 23) + 29360128); // 2.4 MB

    hipLaunchKernelGGL(prep_kernel,    dim3(NH * NKV),          dim3(256), 0, stream, k, v, Kimg, Vimg);
    hipLaunchKernelGGL(attn_fwd,       dim3(NH * CHUNKS_PER_H), dim3(256), 0, stream, q, Kimg, Vimg, o, accW, lmW);
    hipLaunchKernelGGL(combine_kernel, dim3(4096),              dim3(256), 0, stream, o, accW, lmW);
}

// Round 11
// 115.867 us; speedup vs baseline: 2.0857x; 2.0857x over previous
//
#include <hip/hip_runtime.h>

#define SS 4096
#define DD 64
#define NH 16
#define QB 128
#define NQB (SS / QB)      // 32
#define KVT 64
#define NKV (SS / KVT)     // 64
#define TILE_BYTES 8192    // 64 x 64 bf16

// chunking: q-block p has W=2p+2 tiles, split into n=(p>>2)+1 balanced chunks
// (target ~8 tiles). 144 chunks/head, 2304 blocks total.
#define CHUNKS_PER_H 144
#define ACCW_PER_H   112   // chunks with ci>=1
#define LM_PLANE     (16 * CHUNKS_PER_H * 128)   // 294912

typedef float  fx4    __attribute__((ext_vector_type(4)));
typedef __bf16 bf16x8 __attribute__((ext_vector_type(8)));
typedef short  sx4    __attribute__((ext_vector_type(4)));
typedef unsigned short usx4 __attribute__((ext_vector_type(4)));

typedef __attribute__((address_space(1))) const unsigned int GU32;
typedef __attribute__((address_space(3))) unsigned int       LU32;

__device__ __forceinline__ void gload16(const void* g, void* l) {
    __builtin_amdgcn_global_load_lds((GU32*)g, (LU32*)l, 16, 0, 0);
}

__device__ __forceinline__ float fast_exp2(float x) {
    return __builtin_amdgcn_exp2f(x);   // v_exp_f32: 2^x
}

// ---------------- pre-pass: f32 K/V -> bf16 swizzled tile images ----------------
__global__ __launch_bounds__(256)
void prep_kernel(const float* __restrict__ Kg, const float* __restrict__ Vg,
                 char* __restrict__ Kimg, char* __restrict__ Vimg)
{
    __shared__ __bf16 lv[64][72];
    const int tid = threadIdx.x;
    const int h = (int)blockIdx.x >> 6;
    const int t = (int)blockIdx.x & 63;
    const int r = tid >> 2;                       // 0..63
    const size_t rowbase = ((size_t)h * SS + (size_t)t * KVT) * DD;

    // ---- K (swizzled 16B chunks) ----
    {
        char* kdst = Kimg + (size_t)(h * NKV + t) * TILE_BYTES;
        const float* src = Kg + rowbase + (size_t)r * DD;
#pragma unroll
        for (int cc = 0; cc < 2; ++cc) {
            const int c = (tid & 3) * 2 + cc;     // 0..7
            fx4 f0 = *(const fx4*)(src + c * 8);
            fx4 f1 = *(const fx4*)(src + c * 8 + 4);
            bf16x8 b;
#pragma unroll
            for (int j = 0; j < 4; ++j) { b[j] = (__bf16)f0[j]; b[4 + j] = (__bf16)f1[j]; }
            *(bf16x8*)(kdst + r * 128 + ((c ^ (r & 7)) << 4)) = b;
        }
    }

    // ---- V: load tile to LDS (row-major), then write transposed + swizzled ----
    {
        const float* src = Vg + rowbase + (size_t)r * DD + (tid & 3) * 16;
#pragma unroll
        for (int qq = 0; qq < 4; ++qq) {
            fx4 f = *(const fx4*)(src + qq * 4);
#pragma unroll
            for (int j = 0; j < 4; ++j) lv[r][(tid & 3) * 16 + qq * 4 + j] = (__bf16)f[j];
        }
    }
    __syncthreads();
    {
        char* vdst = Vimg + (size_t)(h * NKV + t) * TILE_BYTES;
        const int d = r;                          // VT row
#pragma unroll
        for (int cc = 0; cc < 2; ++cc) {
            const int c = (tid & 3) * 2 + cc;     // k-chunk 0..7
            bf16x8 b;
#pragma unroll
            for (int j = 0; j < 8; ++j) b[j] = lv[c * 8 + j][d];
            *(bf16x8*)(vdst + d * 128 + ((c ^ (d & 7)) << 4)) = b;
        }
    }
}

// ---------------- main kernel: 8 waves x 16 q-rows, uniform KV chunks ----------------
// block b: h = b/144; logical cid = 143 - b%144 (big chunks dispatch first).
// cid -> group m (q-blocks 4m..4m+3, n=m+1 chunks each), p, ci.
// chunk ci: tiles [ci*W/n, (ci+1)*W/n), W = 2p+2.
// ci==0 -> raw f32 acc to Og; ci>=1 -> bf16 acc to accW. l/m per row to lmW.
__global__ __launch_bounds__(512, 8)
void attn_fwd(const float* __restrict__ Qg, const char* __restrict__ Kimg,
              const char* __restrict__ Vimg, float* __restrict__ Og,
              unsigned short* __restrict__ accW, float* __restrict__ lmW)
{
    __shared__ __align__(16) char lK[2][TILE_BYTES];
    __shared__ __align__(16) char lV[2][TILE_BYTES];

    const int tid  = threadIdx.x;
    const int wid  = tid >> 6;                    // 0..7
    const int lane = tid & 63;
    const int lr   = lane & 15;
    const int g    = lane >> 4;

    // ---- chunk decode (all scalar) ----
    const int b = (int)blockIdx.x;                // 0..2303
    const int h = b / CHUNKS_PER_H;
    int r_ = (CHUNKS_PER_H - 1) - (b - h * CHUNKS_PER_H);   // logical cid, reversed
    const int cid = r_;
    int m = 0;
#pragma unroll
    for (int i = 0; i < 7; ++i) {                 // group m starts at 2m(m+1), width 4(m+1)
        if (r_ >= 4 * (i + 1)) { r_ -= 4 * (i + 1); m = i + 1; }
    }
    int p4 = 0;
#pragma unroll
    for (int i = 0; i < 3; ++i) {
        if (r_ >= m + 1) { r_ -= (m + 1); ++p4; }
    }
    const int p  = 4 * m + p4;
    const int ci = r_;
    const int n  = m + 1;
    const int W  = 2 * p + 2;
    const int t0 = (ci * W) / n;
    const int t1 = ((ci + 1) * W) / n;

    const int q0 = p * QB + wid * 16;             // wave owns 16 q rows

    const float* Qh = Qg + (size_t)h * SS * DD;
    float*       Oh = Og + (size_t)h * SS * DD;
    const char*  Kh = Kimg + (size_t)(h * NKV) * TILE_BYTES;
    const char*  Vh = Vimg + (size_t)(h * NKV) * TILE_BYTES;

    const float QSCALE = 0.125f * 1.44269504088896f;   // 1/sqrt(64) * log2(e)

    // Q fragments (held all kernel)
    bf16x8 qa[2];
    {
        const int qrow = q0 + lr;
#pragma unroll
        for (int h2 = 0; h2 < 2; ++h2) {
            const float* src = Qh + (size_t)qrow * DD + h2 * 32 + g * 8;
            fx4 f0 = *(const fx4*)(src);
            fx4 f1 = *(const fx4*)(src + 4);
            bf16x8 tq;
#pragma unroll
            for (int jj = 0; jj < 4; ++jj) {
                tq[jj]     = (__bf16)(f0[jj] * QSCALE);
                tq[jj + 4] = (__bf16)(f1[jj] * QSCALE);
            }
            qa[h2] = tq;
        }
    }

    fx4 acc[4];
#pragma unroll
    for (int d0 = 0; d0 < 4; ++d0) acc[d0] = (fx4){0.f, 0.f, 0.f, 0.f};
    float m_run = -1e30f;           // wave-uniform running max (log2 units)
    float l_run = 0.f;              // lane-local partial row sum

    // staging: waves 0..3 -> K quarter-tiles, waves 4..7 -> V quarter-tiles (2KB each)
#define STAGE(buf, tt)                                                          \
    do {                                                                        \
        const int sw_ = wid & 3;                                                \
        const char* src_ = ((wid < 4) ? Kh : Vh) + (size_t)(tt) * TILE_BYTES    \
                           + sw_ * 2048 + lane * 16;                            \
        char* dst_ = ((wid < 4) ? &lK[buf][0] : &lV[buf][0]) + sw_ * 2048;      \
        gload16(src_,        dst_);                                             \
        gload16(src_ + 1024, dst_ + 1024);                                      \
    } while (0)

    STAGE(0, t0);
    __syncthreads();

    int cur = 0;
    for (int t = t0; t < t1; ++t) {
        if (t + 1 < t1) STAGE(cur ^ 1, t + 1);   // prefetch next tile

        // ---- QK^T (swapped: A=K tile rows, B=Q) ----
        float s[4][4];
        __builtin_amdgcn_s_setprio(1);
#pragma unroll
        for (int ks = 0; ks < 4; ++ks) {
            const int row = ks * 16 + lr;
            const char* base = &lK[cur][row * 128];
            const bf16x8 ka0 = *(const bf16x8*)(base + (((g    ) ^ (row & 7)) << 4));
            const bf16x8 ka1 = *(const bf16x8*)(base + (((g ^ 4) ^ (row & 7)) << 4));
            fx4 st = (fx4){0.f, 0.f, 0.f, 0.f};
            st = __builtin_amdgcn_mfma_f32_16x16x32_bf16(ka0, qa[0], st, 0, 0, 0);
            st = __builtin_amdgcn_mfma_f32_16x16x32_bf16(ka1, qa[1], st, 0, 0, 0);
#pragma unroll
            for (int r = 0; r < 4; ++r) s[ks][r] = st[r];
        }
        __builtin_amdgcn_s_setprio(0);

        // ---- causal mask (tile crosses diagonal iff t >= 2p) ----
        if (t >= 2 * p) {
            const int kv0 = t * KVT;
            const int qrow = q0 + lr;
#pragma unroll
            for (int ks = 0; ks < 4; ++ks)
#pragma unroll
                for (int r = 0; r < 4; ++r) {
                    const int kvi = kv0 + ks * 16 + 4 * g + r;
                    if (kvi > qrow) s[ks][r] = -1e30f;
                }
        }

        // ---- softmax: shuffle-free check, rare wave-uniform rescale ----
        const float tm = fmaxf(
            fmaxf(fmaxf(fmaxf(s[0][0], s[0][1]), fmaxf(s[0][2], s[0][3])),
                  fmaxf(fmaxf(s[1][0], s[1][1]), fmaxf(s[1][2], s[1][3]))),
            fmaxf(fmaxf(fmaxf(s[2][0], s[2][1]), fmaxf(s[2][2], s[2][3])),
                  fmaxf(fmaxf(s[3][0], s[3][1]), fmaxf(s[3][2], s[3][3]))));

        if (__any(tm > m_run + 8.0f)) {           // rare after first tile
            float wm = tm;
            wm = fmaxf(wm, __shfl_xor(wm, 1));
            wm = fmaxf(wm, __shfl_xor(wm, 2));
            wm = fmaxf(wm, __shfl_xor(wm, 4));
            wm = fmaxf(wm, __shfl_xor(wm, 8));
            wm = fmaxf(wm, __shfl_xor(wm, 16));
            wm = fmaxf(wm, __shfl_xor(wm, 32));   // wave max, uniform
            const float alpha = fast_exp2(m_run - wm);
            m_run = wm;
            l_run *= alpha;
#pragma unroll
            for (int d0 = 0; d0 < 4; ++d0) {
                fx4 a = acc[d0];
                a[0] *= alpha; a[1] *= alpha; a[2] *= alpha; a[3] *= alpha;
                acc[d0] = a;
            }
        }

        sx4 pa[4];
        {
#pragma unroll
            for (int ks = 0; ks < 4; ++ks)
#pragma unroll
                for (int r = 0; r < 4; ++r)
                    s[ks][r] = fast_exp2(s[ks][r] - m_run);   // in-place P
            const float u0 = (s[0][0] + s[0][1]) + (s[0][2] + s[0][3]);
            const float u1 = (s[1][0] + s[1][1]) + (s[1][2] + s[1][3]);
            const float u2 = (s[2][0] + s[2][1]) + (s[2][2] + s[2][3]);
            const float u3 = (s[3][0] + s[3][1]) + (s[3][2] + s[3][3]);
            l_run += (u0 + u1) + (u2 + u3);
#pragma unroll
            for (int ks = 0; ks < 4; ++ks) {
                sx4 t4;
#pragma unroll
                for (int jj = 0; jj < 4; ++jj) {
                    const __bf16 pb = (__bf16)s[ks][jj];
                    t4[jj] = __builtin_bit_cast(short, pb);
                }
                pa[ks] = t4;
            }
        }

        // ---- PV: P fragments already in MFMA A-layout; V^T read swizzled ----
        __builtin_amdgcn_s_setprio(1);
#pragma unroll
        for (int ks = 0; ks < 4; ++ks) {
            const int s0 = ks * 2 + (g >> 1);     // k-chunk slot
#pragma unroll
            for (int d0 = 0; d0 < 4; ++d0) {
                const int row = d0 * 16 + lr;
                const sx4 vb = *(const sx4*)(&lV[cur][row * 128 +
                                ((s0 ^ (row & 7)) << 4) + (g & 1) * 8]);
                acc[d0] = __builtin_amdgcn_mfma_f32_16x16x16bf16_1k(pa[ks], vb, acc[d0], 0, 0, 0);
            }
        }
        __builtin_amdgcn_s_setprio(0);

        if (t + 1 < t1) __syncthreads();
        cur ^= 1;
    }

    // ---- epilogue: reduce l across g, write partial + lm ----
    float ls = l_run;
    ls += __shfl_xor(ls, 16);
    ls += __shfl_xor(ls, 32);

    const int rowb = (h * CHUNKS_PER_H + cid) * 128 + wid * 16 + lr;
    if (lane < 16) {
        lmW[rowb]            = m_run;
        lmW[LM_PLANE + rowb] = ls;
    }

    if (ci == 0) {                   // raw f32 acc -> Og
#pragma unroll
        for (int d0 = 0; d0 < 4; ++d0)
#pragma unroll
            for (int r = 0; r < 4; ++r)
                Oh[(size_t)(q0 + 4 * g + r) * DD + d0 * 16 + lr] = acc[d0][r];
    } else {                         // bf16 acc -> accW (dense idx = cid - p - 1)
        const size_t ab = ((size_t)(h * ACCW_PER_H) + (cid - p - 1)) * 8192
                        + (size_t)(wid * 16) * 64;
#pragma unroll
        for (int d0 = 0; d0 < 4; ++d0)
#pragma unroll
            for (int r = 0; r < 4; ++r) {
                const __bf16 pb = (__bf16)acc[d0][r];
                accW[ab + (size_t)(4 * g + r) * 64 + d0 * 16 + lr] =
                    __builtin_bit_cast(unsigned short, pb);
            }
    }
#undef STAGE
}

// ---------------- combine: branchless unrolled 8-way merge ----------------
// grid 4096 = (h, p, rg): 16-row slice rg of q-block (h,p). One thread = one
// row x 4 cols. All stat loads + partial loads issue in parallel (unrolled,
// index-clamped, weight-zeroed padding).
__global__ __launch_bounds__(256)
void combine_kernel(float* __restrict__ Og, const unsigned short* __restrict__ accW,
                    const float* __restrict__ lmW)
{
    const int blk = (int)blockIdx.x;      // 0..4095
    const int rg = blk & 7;
    const int p  = (blk >> 3) & 31;
    const int h  = blk >> 8;

    const int m = p >> 2, n = m + 1;
    const int cid0 = 2 * m * (m + 1) + (p & 3) * n;
    const int lmB  = (h * CHUNKS_PER_H + cid0) * 128;
    const size_t obase = ((size_t)h * SS + (size_t)p * QB) * DD;
    const size_t ab0   = ((size_t)(h * ACCW_PER_H) + (cid0 - p)) * 8192;  // chunk ci=1

    const int row = rg * 16 + ((int)threadIdx.x >> 4);     // 0..127
    const int c4  = ((int)threadIdx.x & 15) * 4;           // 0..60

    // ---- per-row stats: 8-wide, clamped loads, padding weight-zeroed ----
    float mi[8], li[8];
#pragma unroll
    for (int i = 0; i < 8; ++i) {
        const int ic = (i < n) ? i : 0;
        mi[i] = lmW[lmB + ic * 128 + row];
        li[i] = lmW[LM_PLANE + lmB + ic * 128 + row];
    }
#pragma unroll
    for (int i = 0; i < 8; ++i) {
        if (i >= n) { mi[i] = -3.0e38f; li[i] = 0.f; }
    }
    const float mm = fmaxf(fmaxf(fmaxf(mi[0], mi[1]), fmaxf(mi[2], mi[3])),
                           fmaxf(fmaxf(mi[4], mi[5]), fmaxf(mi[6], mi[7])));
    float w[8];
    float den = 0.f;
#pragma unroll
    for (int i = 0; i < 8; ++i) {
        w[i] = fast_exp2(mi[i] - mm);     // exp2(-huge) = 0 for padding
        den += w[i] * li[i];
    }

    // ---- element merge: chunk0 (f32, in Og) + chunks 1..n-1 (bf16, accW) ----
    const size_t oi = obase + (size_t)row * DD + c4;
    fx4 val = *(const fx4*)(&Og[oi]);
    val[0] *= w[0]; val[1] *= w[0]; val[2] *= w[0]; val[3] *= w[0];

#pragma unroll
    for (int i = 1; i < 8; ++i) {
        const int ai = (i < n) ? (i - 1) : 0;              // clamped, always valid
        const usx4 ub = *(const usx4*)(&accW[ab0 + (size_t)ai * 8192 + row * 64 + c4]);
#pragma unroll
        for (int j = 0; j < 4; ++j) {
            const unsigned int bits = ((unsigned int)ub[j]) << 16;
            val[j] += w[i] * __builtin_bit_cast(float, bits);
        }
    }

    const float rinv = 1.f / den;
    val[0] *= rinv; val[1] *= rinv; val[2] *= rinv; val[3] *= rinv;
    *(fx4*)(&Og[oi]) = val;
}

extern "C" void kernel_launch(void* const* d_in, const int* in_sizes, int n_in,
                              void* d_out, int out_size, void* d_ws, size_t ws_size,
                              hipStream_t stream)
{
    (void)in_sizes; (void)n_in; (void)out_size; (void)ws_size;
    const float* q = (const float*)d_in[0];
    const float* k = (const float*)d_in[1];
    const float* v = (const float*)d_in[2];
    float*       o = (float*)d_out;

    char* ws = (char*)d_ws;
    char*           Kimg = ws;                                        // 8 MB
    char*           Vimg = ws + ((size_t)1 << 23);                    // 8 MB
    unsigned short* accW = (unsigned short*)(ws + ((size_t)2 << 23)); // 29.4 MB bf16 partials
    float*          lmW  = (float*)(ws + ((size_t)2 << 23) + 29360128); // 2.4 MB

    hipLaunchKernelGGL(prep_kernel,    dim3(NH * NKV),          dim3(256), 0, stream, k, v, Kimg, Vimg);
    hipLaunchKernelGGL(attn_fwd,       dim3(NH * CHUNKS_PER_H), dim3(512), 0, stream, q, Kimg, Vimg, o, accW, lmW);
    hipLaunchKernelGGL(combine_kernel, dim3(4096),              dim3(256), 0, stream, o, accW, lmW);
}

// Round 12
// 88.886 us; speedup vs baseline: 2.7189x; 1.3035x over previous
//
#include <hip/hip_runtime.h>

#define SS 4096
#define DD 64
#define NH 16
#define QB 128
#define NQB (SS / QB)      // 32
#define KVT 64
#define NKV (SS / KVT)     // 64
#define TILE_BYTES 8192    // 64 x 64 bf16

// chunking: q-block p has W=2p+2 tiles, split into n=(p>>2)+1 balanced chunks
// (target ~8 tiles). 144 chunks/head, 2304 blocks total.
#define CHUNKS_PER_H 144
#define ACCW_PER_H   112   // chunks with ci>=1
#define LM_PLANE     (16 * CHUNKS_PER_H * 128)   // 294912

typedef float  fx4    __attribute__((ext_vector_type(4)));
typedef __bf16 bf16x8 __attribute__((ext_vector_type(8)));
typedef short  sx4    __attribute__((ext_vector_type(4)));
typedef unsigned short usx4 __attribute__((ext_vector_type(4)));

typedef __attribute__((address_space(1))) const unsigned int GU32;
typedef __attribute__((address_space(3))) unsigned int       LU32;

__device__ __forceinline__ void gload16(const void* g, void* l) {
    __builtin_amdgcn_global_load_lds((GU32*)g, (LU32*)l, 16, 0, 0);
}

__device__ __forceinline__ float fast_exp2(float x) {
    return __builtin_amdgcn_exp2f(x);   // v_exp_f32: 2^x
}

// ---------------- pre-pass: f32 K/V -> bf16 swizzled tile images ----------------
__global__ __launch_bounds__(256)
void prep_kernel(const float* __restrict__ Kg, const float* __restrict__ Vg,
                 char* __restrict__ Kimg, char* __restrict__ Vimg)
{
    __shared__ __bf16 lv[64][72];
    const int tid = threadIdx.x;
    const int h = (int)blockIdx.x >> 6;
    const int t = (int)blockIdx.x & 63;
    const int r = tid >> 2;                       // 0..63
    const size_t rowbase = ((size_t)h * SS + (size_t)t * KVT) * DD;

    // ---- K (swizzled 16B chunks) ----
    {
        char* kdst = Kimg + (size_t)(h * NKV + t) * TILE_BYTES;
        const float* src = Kg + rowbase + (size_t)r * DD;
#pragma unroll
        for (int cc = 0; cc < 2; ++cc) {
            const int c = (tid & 3) * 2 + cc;     // 0..7
            fx4 f0 = *(const fx4*)(src + c * 8);
            fx4 f1 = *(const fx4*)(src + c * 8 + 4);
            bf16x8 b;
#pragma unroll
            for (int j = 0; j < 4; ++j) { b[j] = (__bf16)f0[j]; b[4 + j] = (__bf16)f1[j]; }
            *(bf16x8*)(kdst + r * 128 + ((c ^ (r & 7)) << 4)) = b;
        }
    }

    // ---- V: load tile to LDS (row-major), then write transposed + swizzled ----
    {
        const float* src = Vg + rowbase + (size_t)r * DD + (tid & 3) * 16;
#pragma unroll
        for (int qq = 0; qq < 4; ++qq) {
            fx4 f = *(const fx4*)(src + qq * 4);
#pragma unroll
            for (int j = 0; j < 4; ++j) lv[r][(tid & 3) * 16 + qq * 4 + j] = (__bf16)f[j];
        }
    }
    __syncthreads();
    {
        char* vdst = Vimg + (size_t)(h * NKV + t) * TILE_BYTES;
        const int d = r;                          // VT row
#pragma unroll
        for (int cc = 0; cc < 2; ++cc) {
            const int c = (tid & 3) * 2 + cc;     // k-chunk 0..7
            bf16x8 b;
#pragma unroll
            for (int j = 0; j < 8; ++j) b[j] = lv[c * 8 + j][d];
            *(bf16x8*)(vdst + d * 128 + ((c ^ (d & 7)) << 4)) = b;
        }
    }
}

// ---------------- main kernel: 4 waves x 32 q-rows, counted-vmcnt pipeline ----------------
// block b: h = b/144; logical cid = 143 - b%144 (big chunks dispatch first).
// chunk ci: tiles [ci*W/n, (ci+1)*W/n), W = 2p+2. 3 LDS buffers, 2-deep prefetch;
// per-tile sync = "s_waitcnt vmcnt(4); s_barrier" (never drains the newest tile).
__global__ __launch_bounds__(256, 3)
void attn_fwd(const float* __restrict__ Qg, const char* __restrict__ Kimg,
              const char* __restrict__ Vimg, float* __restrict__ Og,
              unsigned short* __restrict__ accW, float* __restrict__ lmW)
{
    __shared__ __align__(16) char lK[3][TILE_BYTES];
    __shared__ __align__(16) char lV[3][TILE_BYTES];   // 48 KB total

    const int tid  = threadIdx.x;
    const int wid  = tid >> 6;                    // 0..3
    const int lane = tid & 63;
    const int lr   = lane & 15;
    const int g    = lane >> 4;

    // ---- chunk decode (all scalar) ----
    const int b = (int)blockIdx.x;                // 0..2303
    const int h = b / CHUNKS_PER_H;
    int r_ = (CHUNKS_PER_H - 1) - (b - h * CHUNKS_PER_H);   // logical cid, reversed
    const int cid = r_;
    int m = 0;
#pragma unroll
    for (int i = 0; i < 7; ++i) {                 // group m starts at 2m(m+1), width 4(m+1)
        if (r_ >= 4 * (i + 1)) { r_ -= 4 * (i + 1); m = i + 1; }
    }
    int p4 = 0;
#pragma unroll
    for (int i = 0; i < 3; ++i) {
        if (r_ >= m + 1) { r_ -= (m + 1); ++p4; }
    }
    const int p  = 4 * m + p4;
    const int ci = r_;
    const int n  = m + 1;
    const int W  = 2 * p + 2;
    const int t0 = (ci * W) / n;
    const int t1 = ((ci + 1) * W) / n;

    const int q0 = p * QB + wid * 32;             // wave owns 32 q rows (2 subtiles)

    const float* Qh = Qg + (size_t)h * SS * DD;
    float*       Oh = Og + (size_t)h * SS * DD;
    const char*  Kh = Kimg + (size_t)(h * NKV) * TILE_BYTES;
    const char*  Vh = Vimg + (size_t)(h * NKV) * TILE_BYTES;

    const float QSCALE = 0.125f * 1.44269504088896f;   // 1/sqrt(64) * log2(e)

    // Q fragments (held all kernel)
    bf16x8 qa[2][2];
#pragma unroll
    for (int u = 0; u < 2; ++u) {
        const int qrow = q0 + 16 * u + lr;
#pragma unroll
        for (int h2 = 0; h2 < 2; ++h2) {
            const float* src = Qh + (size_t)qrow * DD + h2 * 32 + g * 8;
            fx4 f0 = *(const fx4*)(src);
            fx4 f1 = *(const fx4*)(src + 4);
            bf16x8 tq;
#pragma unroll
            for (int jj = 0; jj < 4; ++jj) {
                tq[jj]     = (__bf16)(f0[jj] * QSCALE);
                tq[jj + 4] = (__bf16)(f1[jj] * QSCALE);
            }
            qa[u][h2] = tq;
        }
    }

    fx4 acc[2][4];
#pragma unroll
    for (int u = 0; u < 2; ++u)
#pragma unroll
        for (int d0 = 0; d0 < 4; ++d0) acc[u][d0] = (fx4){0.f, 0.f, 0.f, 0.f};
    float m_run = -1e30f;           // wave-uniform running max (log2 units)
    float l_run[2] = {0.f, 0.f};    // lane-local partial row sums

    // staging: waves 0,1 -> K tile halves; waves 2,3 -> V tile halves (4KB/wave,
    // 4 gload16 per thread per tile => vmcnt granularity of 4 per STAGE)
#define STAGE(buf, tt)                                                          \
    do {                                                                        \
        const char* img_ = (wid < 2) ? Kh : Vh;                                 \
        char* dst_ = ((wid < 2) ? &lK[buf][0] : &lV[buf][0]) + (wid & 1) * 4096;\
        const char* src_ = img_ + (size_t)(tt) * TILE_BYTES + (wid & 1) * 4096  \
                           + lane * 16;                                         \
        gload16(src_,        dst_);                                             \
        gload16(src_ + 1024, dst_ + 1024);                                      \
        gload16(src_ + 2048, dst_ + 2048);                                      \
        gload16(src_ + 3072, dst_ + 3072);                                      \
    } while (0)

    // ---- prologue: stage t0 (+ t0+1), wait only for t0, barrier ----
    STAGE(0, t0);
    if (t0 + 1 < t1) {
        STAGE(1, t0 + 1);
        asm volatile("s_waitcnt vmcnt(4)\n\ts_barrier" ::: "memory");
    } else {
        asm volatile("s_waitcnt vmcnt(0)\n\ts_barrier" ::: "memory");
    }
    __builtin_amdgcn_sched_barrier(0);

    int cur = 0;
    for (int t = t0; t < t1; ++t) {
        const int nx2 = (cur >= 1) ? cur - 1 : cur + 2;   // (cur+2)%3
        if (t + 2 < t1) STAGE(nx2, t + 2);   // 2-deep prefetch

        // ---- QK^T (swapped: A=K tile rows, B=Q) ----
        float s[2][4][4];
        __builtin_amdgcn_s_setprio(1);
#pragma unroll
        for (int ks = 0; ks < 4; ++ks) {
            const int row = ks * 16 + lr;
            const char* base = &lK[cur][row * 128];
            const bf16x8 ka0 = *(const bf16x8*)(base + (((g    ) ^ (row & 7)) << 4));
            const bf16x8 ka1 = *(const bf16x8*)(base + (((g ^ 4) ^ (row & 7)) << 4));
#pragma unroll
            for (int u = 0; u < 2; ++u) {
                fx4 st = (fx4){0.f, 0.f, 0.f, 0.f};
                st = __builtin_amdgcn_mfma_f32_16x16x32_bf16(ka0, qa[u][0], st, 0, 0, 0);
                st = __builtin_amdgcn_mfma_f32_16x16x32_bf16(ka1, qa[u][1], st, 0, 0, 0);
#pragma unroll
                for (int r = 0; r < 4; ++r) s[u][ks][r] = st[r];
            }
        }
        __builtin_amdgcn_s_setprio(0);

        // ---- causal mask (tile crosses diagonal iff t >= 2p) ----
        if (t >= 2 * p) {
            const int kv0 = t * KVT;
#pragma unroll
            for (int u = 0; u < 2; ++u) {
                const int qrow = q0 + 16 * u + lr;
#pragma unroll
                for (int ks = 0; ks < 4; ++ks)
#pragma unroll
                    for (int r = 0; r < 4; ++r) {
                        const int kvi = kv0 + ks * 16 + 4 * g + r;
                        if (kvi > qrow) s[u][ks][r] = -1e30f;
                    }
            }
        }

        // ---- softmax: shuffle-free check, rare wave-uniform rescale ----
        float m4[2][4];
#pragma unroll
        for (int u = 0; u < 2; ++u)
#pragma unroll
            for (int ks = 0; ks < 4; ++ks)
                m4[u][ks] = fmaxf(fmaxf(s[u][ks][0], s[u][ks][1]),
                                  fmaxf(s[u][ks][2], s[u][ks][3]));
        const float tm = fmaxf(
            fmaxf(fmaxf(m4[0][0], m4[0][1]), fmaxf(m4[0][2], m4[0][3])),
            fmaxf(fmaxf(m4[1][0], m4[1][1]), fmaxf(m4[1][2], m4[1][3])));

        if (__any(tm > m_run + 8.0f)) {           // rare after first tile
            float wm = tm;
            wm = fmaxf(wm, __shfl_xor(wm, 1));
            wm = fmaxf(wm, __shfl_xor(wm, 2));
            wm = fmaxf(wm, __shfl_xor(wm, 4));
            wm = fmaxf(wm, __shfl_xor(wm, 8));
            wm = fmaxf(wm, __shfl_xor(wm, 16));
            wm = fmaxf(wm, __shfl_xor(wm, 32));   // wave max, uniform
            const float alpha = fast_exp2(m_run - wm);
            m_run = wm;
            l_run[0] *= alpha; l_run[1] *= alpha;
#pragma unroll
            for (int u = 0; u < 2; ++u)
#pragma unroll
                for (int d0 = 0; d0 < 4; ++d0) {
                    fx4 a = acc[u][d0];
                    a[0] *= alpha; a[1] *= alpha; a[2] *= alpha; a[3] *= alpha;
                    acc[u][d0] = a;
                }
        }

        sx4 pa[2][4];
#pragma unroll
        for (int u = 0; u < 2; ++u) {
#pragma unroll
            for (int ks = 0; ks < 4; ++ks)
#pragma unroll
                for (int r = 0; r < 4; ++r)
                    s[u][ks][r] = fast_exp2(s[u][ks][r] - m_run);   // in-place P
            const float u0 = (s[u][0][0] + s[u][0][1]) + (s[u][0][2] + s[u][0][3]);
            const float u1 = (s[u][1][0] + s[u][1][1]) + (s[u][1][2] + s[u][1][3]);
            const float u2 = (s[u][2][0] + s[u][2][1]) + (s[u][2][2] + s[u][2][3]);
            const float u3 = (s[u][3][0] + s[u][3][1]) + (s[u][3][2] + s[u][3][3]);
            l_run[u] += (u0 + u1) + (u2 + u3);
#pragma unroll
            for (int ks = 0; ks < 4; ++ks) {
                sx4 t4;
#pragma unroll
                for (int jj = 0; jj < 4; ++jj) {
                    const __bf16 pb = (__bf16)s[u][ks][jj];
                    t4[jj] = __builtin_bit_cast(short, pb);
                }
                pa[u][ks] = t4;
            }
        }

        // ---- PV: P fragments already in MFMA A-layout; V^T read swizzled ----
        __builtin_amdgcn_s_setprio(1);
#pragma unroll
        for (int ks = 0; ks < 4; ++ks) {
            const int s0 = ks * 2 + (g >> 1);     // k-chunk slot
#pragma unroll
            for (int d0 = 0; d0 < 4; ++d0) {
                const int row = d0 * 16 + lr;
                const sx4 vb = *(const sx4*)(&lV[cur][row * 128 +
                                ((s0 ^ (row & 7)) << 4) + (g & 1) * 8]);
                acc[0][d0] = __builtin_amdgcn_mfma_f32_16x16x16bf16_1k(pa[0][ks], vb, acc[0][d0], 0, 0, 0);
                acc[1][d0] = __builtin_amdgcn_mfma_f32_16x16x16bf16_1k(pa[1][ks], vb, acc[1][d0], 0, 0, 0);
            }
        }
        __builtin_amdgcn_s_setprio(0);

        // ---- counted sync: tile t+1 resident, tile t+2 stays in flight ----
        if (t + 1 < t1) {
            __builtin_amdgcn_sched_barrier(0);
            if (t + 2 < t1)
                asm volatile("s_waitcnt vmcnt(4)\n\ts_barrier" ::: "memory");
            else
                asm volatile("s_waitcnt vmcnt(0)\n\ts_barrier" ::: "memory");
            __builtin_amdgcn_sched_barrier(0);
        }
        cur = (cur == 2) ? 0 : cur + 1;
    }

    // ---- epilogue: reduce l across g, write partial + lm ----
    float ls0 = l_run[0];
    ls0 += __shfl_xor(ls0, 16);
    ls0 += __shfl_xor(ls0, 32);
    float ls1 = l_run[1];
    ls1 += __shfl_xor(ls1, 16);
    ls1 += __shfl_xor(ls1, 32);

    const int rowb = (h * CHUNKS_PER_H + cid) * 128 + wid * 32 + lr;
    if (lane < 16) {
        lmW[rowb]                  = m_run;
        lmW[rowb + 16]             = m_run;
        lmW[LM_PLANE + rowb]       = ls0;
        lmW[LM_PLANE + rowb + 16]  = ls1;
    }

    if (ci == 0) {                   // raw f32 acc -> Og
#pragma unroll
        for (int u = 0; u < 2; ++u)
#pragma unroll
            for (int d0 = 0; d0 < 4; ++d0)
#pragma unroll
                for (int r = 0; r < 4; ++r)
                    Oh[(size_t)(q0 + 16 * u + 4 * g + r) * DD + d0 * 16 + lr] = acc[u][d0][r];
    } else {                         // bf16 acc -> accW (dense idx = cid - p - 1)
        const size_t ab = ((size_t)(h * ACCW_PER_H) + (cid - p - 1)) * 8192
                        + (size_t)(wid * 32) * 64;
#pragma unroll
        for (int u = 0; u < 2; ++u)
#pragma unroll
            for (int d0 = 0; d0 < 4; ++d0)
#pragma unroll
                for (int r = 0; r < 4; ++r) {
                    const __bf16 pb = (__bf16)acc[u][d0][r];
                    accW[ab + (size_t)(16 * u + 4 * g + r) * 64 + d0 * 16 + lr] =
                        __builtin_bit_cast(unsigned short, pb);
                }
    }
#undef STAGE
}

// ---------------- combine: branchless unrolled 8-way merge ----------------
__global__ __launch_bounds__(256)
void combine_kernel(float* __restrict__ Og, const unsigned short* __restrict__ accW,
                    const float* __restrict__ lmW)
{
    const int blk = (int)blockIdx.x;      // 0..4095
    const int rg = blk & 7;
    const int p  = (blk >> 3) & 31;
    const int h  = blk >> 8;

    const int m = p >> 2, n = m + 1;
    const int cid0 = 2 * m * (m + 1) + (p & 3) * n;
    const int lmB  = (h * CHUNKS_PER_H + cid0) * 128;
    const size_t obase = ((size_t)h * SS + (size_t)p * QB) * DD;
    const size_t ab0   = ((size_t)(h * ACCW_PER_H) + (cid0 - p)) * 8192;  // chunk ci=1

    const int row = rg * 16 + ((int)threadIdx.x >> 4);     // 0..127
    const int c4  = ((int)threadIdx.x & 15) * 4;           // 0..60

    // ---- per-row stats: 8-wide, clamped loads, padding weight-zeroed ----
    float mi[8], li[8];
#pragma unroll
    for (int i = 0; i < 8; ++i) {
        const int ic = (i < n) ? i : 0;
        mi[i] = lmW[lmB + ic * 128 + row];
        li[i] = lmW[LM_PLANE + lmB + ic * 128 + row];
    }
#pragma unroll
    for (int i = 0; i < 8; ++i) {
        if (i >= n) { mi[i] = -3.0e38f; li[i] = 0.f; }
    }
    const float mm = fmaxf(fmaxf(fmaxf(mi[0], mi[1]), fmaxf(mi[2], mi[3])),
                           fmaxf(fmaxf(mi[4], mi[5]), fmaxf(mi[6], mi[7])));
    float w[8];
    float den = 0.f;
#pragma unroll
    for (int i = 0; i < 8; ++i) {
        w[i] = fast_exp2(mi[i] - mm);     // exp2(-huge) = 0 for padding
        den += w[i] * li[i];
    }

    // ---- element merge: chunk0 (f32, in Og) + chunks 1..n-1 (bf16, accW) ----
    const size_t oi = obase + (size_t)row * DD + c4;
    fx4 val = *(const fx4*)(&Og[oi]);
    val[0] *= w[0]; val[1] *= w[0]; val[2] *= w[0]; val[3] *= w[0];

#pragma unroll
    for (int i = 1; i < 8; ++i) {
        const int ai = (i < n) ? (i - 1) : 0;              // clamped, always valid
        const usx4 ub = *(const usx4*)(&accW[ab0 + (size_t)ai * 8192 + row * 64 + c4]);
#pragma unroll
        for (int j = 0; j < 4; ++j) {
            const unsigned int bits = ((unsigned int)ub[j]) << 16;
            val[j] += w[i] * __builtin_bit_cast(float, bits);
        }
    }

    const float rinv = 1.f / den;
    val[0] *= rinv; val[1] *= rinv; val[2] *= rinv; val[3] *= rinv;
    *(fx4*)(&Og[oi]) = val;
}

extern "C" void kernel_launch(void* const* d_in, const int* in_sizes, int n_in,
                              void* d_out, int out_size, void* d_ws, size_t ws_size,
                              hipStream_t stream)
{
    (void)in_sizes; (void)n_in; (void)out_size; (void)ws_size;
    const float* q = (const float*)d_in[0];
    const float* k = (const float*)d_in[1];
    const float* v = (const float*)d_in[2];
    float*       o = (float*)d_out;

    char* ws = (char*)d_ws;
    char*           Kimg = ws;                                        // 8 MB
    char*           Vimg = ws + ((size_t)1 << 23);                    // 8 MB
    unsigned short* accW = (unsigned short*)(ws + ((size_t)2 << 23)); // 29.4 MB bf16 partials
    float*          lmW  = (float*)(ws + ((size_t)2 << 23) + 29360128); // 2.4 MB

    hipLaunchKernelGGL(prep_kernel,    dim3(NH * NKV),          dim3(256), 0, stream, k, v, Kimg, Vimg);
    hipLaunchKernelGGL(attn_fwd,       dim3(NH * CHUNKS_PER_H), dim3(256), 0, stream, q, Kimg, Vimg, o, accW, lmW);
    hipLaunchKernelGGL(combine_kernel, dim3(4096),              dim3(256), 0, stream, o, accW, lmW);
}

// Round 13
// 86.921 us; speedup vs baseline: 2.7803x; 1.0226x over previous
//
#include <hip/hip_runtime.h>

#define SS 4096
#define DD 64
#define NH 16
#define QB 128
#define NQB (SS / QB)      // 32
#define KVT 64
#define NKV (SS / KVT)     // 64
#define TILE_BYTES 8192    // 64 x 64 bf16

// chunking: q-block p has W=2p+2 tiles, split into n=(p>>2)+1 balanced chunks
// (target ~8 tiles). 144 chunks/head, 2304 blocks total.
#define CHUNKS_PER_H 144
#define ACCW_PER_H   112   // chunks with ci>=1
#define LM_PLANE     (16 * CHUNKS_PER_H * 128)   // 294912

typedef float  fx4    __attribute__((ext_vector_type(4)));
typedef __bf16 bf16x8 __attribute__((ext_vector_type(8)));
typedef short  sx4    __attribute__((ext_vector_type(4)));
typedef unsigned short usx4 __attribute__((ext_vector_type(4)));

typedef __attribute__((address_space(1))) const unsigned int GU32;
typedef __attribute__((address_space(3))) unsigned int       LU32;

__device__ __forceinline__ void gload16(const void* g, void* l) {
    __builtin_amdgcn_global_load_lds((GU32*)g, (LU32*)l, 16, 0, 0);
}

__device__ __forceinline__ float fast_exp2(float x) {
    return __builtin_amdgcn_exp2f(x);   // v_exp_f32: 2^x
}

// ---------------- pre-pass: f32 K/V -> bf16 swizzled tile images ----------------
__global__ __launch_bounds__(256)
void prep_kernel(const float* __restrict__ Kg, const float* __restrict__ Vg,
                 char* __restrict__ Kimg, char* __restrict__ Vimg)
{
    __shared__ __bf16 lv[64][72];
    const int tid = threadIdx.x;
    const int h = (int)blockIdx.x >> 6;
    const int t = (int)blockIdx.x & 63;
    const int r = tid >> 2;                       // 0..63
    const size_t rowbase = ((size_t)h * SS + (size_t)t * KVT) * DD;

    // ---- K (swizzled 16B chunks) ----
    {
        char* kdst = Kimg + (size_t)(h * NKV + t) * TILE_BYTES;
        const float* src = Kg + rowbase + (size_t)r * DD;
#pragma unroll
        for (int cc = 0; cc < 2; ++cc) {
            const int c = (tid & 3) * 2 + cc;     // 0..7
            fx4 f0 = *(const fx4*)(src + c * 8);
            fx4 f1 = *(const fx4*)(src + c * 8 + 4);
            bf16x8 b;
#pragma unroll
            for (int j = 0; j < 4; ++j) { b[j] = (__bf16)f0[j]; b[4 + j] = (__bf16)f1[j]; }
            *(bf16x8*)(kdst + r * 128 + ((c ^ (r & 7)) << 4)) = b;
        }
    }

    // ---- V: load tile to LDS (row-major), then write transposed + swizzled ----
    {
        const float* src = Vg + rowbase + (size_t)r * DD + (tid & 3) * 16;
#pragma unroll
        for (int qq = 0; qq < 4; ++qq) {
            fx4 f = *(const fx4*)(src + qq * 4);
#pragma unroll
            for (int j = 0; j < 4; ++j) lv[r][(tid & 3) * 16 + qq * 4 + j] = (__bf16)f[j];
        }
    }
    __syncthreads();
    {
        char* vdst = Vimg + (size_t)(h * NKV + t) * TILE_BYTES;
        const int d = r;                          // VT row
#pragma unroll
        for (int cc = 0; cc < 2; ++cc) {
            const int c = (tid & 3) * 2 + cc;     // k-chunk 0..7
            bf16x8 b;
#pragma unroll
            for (int j = 0; j < 8; ++j) b[j] = lv[c * 8 + j][d];
            *(bf16x8*)(vdst + d * 128 + ((c ^ (d & 7)) << 4)) = b;
        }
    }
}

// ---------------- main kernel: 4 waves x 32 q-rows, counted-vmcnt pipeline ----------------
// XCD-aware decode: xcd = b&7 (round-robin dispatch), slot = b>>3;
//   h = xcd + 8*(slot&1), cid = 143 - (slot>>1)  -> each XCD serves exactly
//   2 heads (2 MB of K/V image, fits 4 MB XCD-L2); big chunks dispatch first.
// chunk ci: tiles [ci*W/n, (ci+1)*W/n), W = 2p+2. 3 LDS buffers, 2-deep prefetch;
// per-tile sync = "s_waitcnt vmcnt(4); s_barrier" (never drains the newest tile).
__global__ __launch_bounds__(256, 3)
void attn_fwd(const float* __restrict__ Qg, const char* __restrict__ Kimg,
              const char* __restrict__ Vimg, float* __restrict__ Og,
              unsigned short* __restrict__ accW, float* __restrict__ lmW)
{
    __shared__ __align__(16) char lK[3][TILE_BYTES];
    __shared__ __align__(16) char lV[3][TILE_BYTES];   // 48 KB total

    const int tid  = threadIdx.x;
    const int wid  = tid >> 6;                    // 0..3
    const int lane = tid & 63;
    const int lr   = lane & 15;
    const int g    = lane >> 4;

    // ---- XCD-aware chunk decode (all scalar) ----
    const int b    = (int)blockIdx.x;             // 0..2303
    const int xcd  = b & 7;
    const int slot = b >> 3;                      // 0..287
    const int h    = xcd + ((slot & 1) << 3);
    int r_ = (CHUNKS_PER_H - 1) - (slot >> 1);    // logical cid, big-first
    const int cid = r_;
    int m = 0;
#pragma unroll
    for (int i = 0; i < 7; ++i) {                 // group m starts at 2m(m+1), width 4(m+1)
        if (r_ >= 4 * (i + 1)) { r_ -= 4 * (i + 1); m = i + 1; }
    }
    int p4 = 0;
#pragma unroll
    for (int i = 0; i < 3; ++i) {
        if (r_ >= m + 1) { r_ -= (m + 1); ++p4; }
    }
    const int p  = 4 * m + p4;
    const int ci = r_;
    const int n  = m + 1;
    const int W  = 2 * p + 2;
    const int t0 = (ci * W) / n;
    const int t1 = ((ci + 1) * W) / n;

    const int q0 = p * QB + wid * 32;             // wave owns 32 q rows (2 subtiles)

    const float* Qh = Qg + (size_t)h * SS * DD;
    float*       Oh = Og + (size_t)h * SS * DD;
    const char*  Kh = Kimg + (size_t)(h * NKV) * TILE_BYTES;
    const char*  Vh = Vimg + (size_t)(h * NKV) * TILE_BYTES;

    const float QSCALE = 0.125f * 1.44269504088896f;   // 1/sqrt(64) * log2(e)

    // Q fragments (held all kernel)
    bf16x8 qa[2][2];
#pragma unroll
    for (int u = 0; u < 2; ++u) {
        const int qrow = q0 + 16 * u + lr;
#pragma unroll
        for (int h2 = 0; h2 < 2; ++h2) {
            const float* src = Qh + (size_t)qrow * DD + h2 * 32 + g * 8;
            fx4 f0 = *(const fx4*)(src);
            fx4 f1 = *(const fx4*)(src + 4);
            bf16x8 tq;
#pragma unroll
            for (int jj = 0; jj < 4; ++jj) {
                tq[jj]     = (__bf16)(f0[jj] * QSCALE);
                tq[jj + 4] = (__bf16)(f1[jj] * QSCALE);
            }
            qa[u][h2] = tq;
        }
    }

    fx4 acc[2][4];
#pragma unroll
    for (int u = 0; u < 2; ++u)
#pragma unroll
        for (int d0 = 0; d0 < 4; ++d0) acc[u][d0] = (fx4){0.f, 0.f, 0.f, 0.f};
    float m_run = -1e30f;           // wave-uniform running max (log2 units)
    float l_run[2] = {0.f, 0.f};    // lane-local partial row sums

    // staging: waves 0,1 -> K tile halves; waves 2,3 -> V tile halves (4KB/wave,
    // 4 gload16 per thread per tile => vmcnt granularity of 4 per STAGE)
#define STAGE(buf, tt)                                                          \
    do {                                                                        \
        const char* img_ = (wid < 2) ? Kh : Vh;                                 \
        char* dst_ = ((wid < 2) ? &lK[buf][0] : &lV[buf][0]) + (wid & 1) * 4096;\
        const char* src_ = img_ + (size_t)(tt) * TILE_BYTES + (wid & 1) * 4096  \
                           + lane * 16;                                         \
        gload16(src_,        dst_);                                             \
        gload16(src_ + 1024, dst_ + 1024);                                      \
        gload16(src_ + 2048, dst_ + 2048);                                      \
        gload16(src_ + 3072, dst_ + 3072);                                      \
    } while (0)

    // ---- prologue: stage t0 (+ t0+1), wait only for t0, barrier ----
    STAGE(0, t0);
    if (t0 + 1 < t1) {
        STAGE(1, t0 + 1);
        asm volatile("s_waitcnt vmcnt(4)\n\ts_barrier" ::: "memory");
    } else {
        asm volatile("s_waitcnt vmcnt(0)\n\ts_barrier" ::: "memory");
    }
    __builtin_amdgcn_sched_barrier(0);

    int cur = 0;
    for (int t = t0; t < t1; ++t) {
        const int nx2 = (cur >= 1) ? cur - 1 : cur + 2;   // (cur+2)%3
        if (t + 2 < t1) STAGE(nx2, t + 2);   // 2-deep prefetch

        // ---- QK^T (swapped: A=K tile rows, B=Q) ----
        float s[2][4][4];
        __builtin_amdgcn_s_setprio(1);
#pragma unroll
        for (int ks = 0; ks < 4; ++ks) {
            const int row = ks * 16 + lr;
            const char* base = &lK[cur][row * 128];
            const bf16x8 ka0 = *(const bf16x8*)(base + (((g    ) ^ (row & 7)) << 4));
            const bf16x8 ka1 = *(const bf16x8*)(base + (((g ^ 4) ^ (row & 7)) << 4));
#pragma unroll
            for (int u = 0; u < 2; ++u) {
                fx4 st = (fx4){0.f, 0.f, 0.f, 0.f};
                st = __builtin_amdgcn_mfma_f32_16x16x32_bf16(ka0, qa[u][0], st, 0, 0, 0);
                st = __builtin_amdgcn_mfma_f32_16x16x32_bf16(ka1, qa[u][1], st, 0, 0, 0);
#pragma unroll
                for (int r = 0; r < 4; ++r) s[u][ks][r] = st[r];
            }
        }
        __builtin_amdgcn_s_setprio(0);

        // ---- causal mask (tile crosses diagonal iff t >= 2p) ----
        if (t >= 2 * p) {
            const int kv0 = t * KVT;
#pragma unroll
            for (int u = 0; u < 2; ++u) {
                const int qrow = q0 + 16 * u + lr;
#pragma unroll
                for (int ks = 0; ks < 4; ++ks)
#pragma unroll
                    for (int r = 0; r < 4; ++r) {
                        const int kvi = kv0 + ks * 16 + 4 * g + r;
                        if (kvi > qrow) s[u][ks][r] = -1e30f;
                    }
            }
        }

        // ---- softmax: shuffle-free check, rare wave-uniform rescale ----
        float m4[2][4];
#pragma unroll
        for (int u = 0; u < 2; ++u)
#pragma unroll
            for (int ks = 0; ks < 4; ++ks)
                m4[u][ks] = fmaxf(fmaxf(s[u][ks][0], s[u][ks][1]),
                                  fmaxf(s[u][ks][2], s[u][ks][3]));
        const float tm = fmaxf(
            fmaxf(fmaxf(m4[0][0], m4[0][1]), fmaxf(m4[0][2], m4[0][3])),
            fmaxf(fmaxf(m4[1][0], m4[1][1]), fmaxf(m4[1][2], m4[1][3])));

        if (__any(tm > m_run + 8.0f)) {           // rare after first tile
            float wm = tm;
            wm = fmaxf(wm, __shfl_xor(wm, 1));
            wm = fmaxf(wm, __shfl_xor(wm, 2));
            wm = fmaxf(wm, __shfl_xor(wm, 4));
            wm = fmaxf(wm, __shfl_xor(wm, 8));
            wm = fmaxf(wm, __shfl_xor(wm, 16));
            wm = fmaxf(wm, __shfl_xor(wm, 32));   // wave max, uniform
            const float alpha = fast_exp2(m_run - wm);
            m_run = wm;
            l_run[0] *= alpha; l_run[1] *= alpha;
#pragma unroll
            for (int u = 0; u < 2; ++u)
#pragma unroll
                for (int d0 = 0; d0 < 4; ++d0) {
                    fx4 a = acc[u][d0];
                    a[0] *= alpha; a[1] *= alpha; a[2] *= alpha; a[3] *= alpha;
                    acc[u][d0] = a;
                }
        }

        sx4 pa[2][4];
#pragma unroll
        for (int u = 0; u < 2; ++u) {
#pragma unroll
            for (int ks = 0; ks < 4; ++ks)
#pragma unroll
                for (int r = 0; r < 4; ++r)
                    s[u][ks][r] = fast_exp2(s[u][ks][r] - m_run);   // in-place P
            const float u0 = (s[u][0][0] + s[u][0][1]) + (s[u][0][2] + s[u][0][3]);
            const float u1 = (s[u][1][0] + s[u][1][1]) + (s[u][1][2] + s[u][1][3]);
            const float u2 = (s[u][2][0] + s[u][2][1]) + (s[u][2][2] + s[u][2][3]);
            const float u3 = (s[u][3][0] + s[u][3][1]) + (s[u][3][2] + s[u][3][3]);
            l_run[u] += (u0 + u1) + (u2 + u3);
#pragma unroll
            for (int ks = 0; ks < 4; ++ks) {
                sx4 t4;
#pragma unroll
                for (int jj = 0; jj < 4; ++jj) {
                    const __bf16 pb = (__bf16)s[u][ks][jj];
                    t4[jj] = __builtin_bit_cast(short, pb);
                }
                pa[u][ks] = t4;
            }
        }

        // ---- PV: P fragments already in MFMA A-layout; V^T read swizzled ----
        __builtin_amdgcn_s_setprio(1);
#pragma unroll
        for (int ks = 0; ks < 4; ++ks) {
            const int s0 = ks * 2 + (g >> 1);     // k-chunk slot
#pragma unroll
            for (int d0 = 0; d0 < 4; ++d0) {
                const int row = d0 * 16 + lr;
                const sx4 vb = *(const sx4*)(&lV[cur][row * 128 +
                                ((s0 ^ (row & 7)) << 4) + (g & 1) * 8]);
                acc[0][d0] = __builtin_amdgcn_mfma_f32_16x16x16bf16_1k(pa[0][ks], vb, acc[0][d0], 0, 0, 0);
                acc[1][d0] = __builtin_amdgcn_mfma_f32_16x16x16bf16_1k(pa[1][ks], vb, acc[1][d0], 0, 0, 0);
            }
        }
        __builtin_amdgcn_s_setprio(0);

        // ---- counted sync: tile t+1 resident, tile t+2 stays in flight ----
        if (t + 1 < t1) {
            __builtin_amdgcn_sched_barrier(0);
            if (t + 2 < t1)
                asm volatile("s_waitcnt vmcnt(4)\n\ts_barrier" ::: "memory");
            else
                asm volatile("s_waitcnt vmcnt(0)\n\ts_barrier" ::: "memory");
            __builtin_amdgcn_sched_barrier(0);
        }
        cur = (cur == 2) ? 0 : cur + 1;
    }

    // ---- epilogue: reduce l across g, write partial + lm ----
    float ls0 = l_run[0];
    ls0 += __shfl_xor(ls0, 16);
    ls0 += __shfl_xor(ls0, 32);
    float ls1 = l_run[1];
    ls1 += __shfl_xor(ls1, 16);
    ls1 += __shfl_xor(ls1, 32);

    const int rowb = (h * CHUNKS_PER_H + cid) * 128 + wid * 32 + lr;
    if (lane < 16) {
        lmW[rowb]                  = m_run;
        lmW[rowb + 16]             = m_run;
        lmW[LM_PLANE + rowb]       = ls0;
        lmW[LM_PLANE + rowb + 16]  = ls1;
    }

    if (ci == 0) {                   // raw f32 acc -> Og
#pragma unroll
        for (int u = 0; u < 2; ++u)
#pragma unroll
            for (int d0 = 0; d0 < 4; ++d0)
#pragma unroll
                for (int r = 0; r < 4; ++r)
                    Oh[(size_t)(q0 + 16 * u + 4 * g + r) * DD + d0 * 16 + lr] = acc[u][d0][r];
    } else {                         // bf16 acc -> accW (dense idx = cid - p - 1)
        const size_t ab = ((size_t)(h * ACCW_PER_H) + (cid - p - 1)) * 8192
                        + (size_t)(wid * 32) * 64;
#pragma unroll
        for (int u = 0; u < 2; ++u)
#pragma unroll
            for (int d0 = 0; d0 < 4; ++d0)
#pragma unroll
                for (int r = 0; r < 4; ++r) {
                    const __bf16 pb = (__bf16)acc[u][d0][r];
                    accW[ab + (size_t)(16 * u + 4 * g + r) * 64 + d0 * 16 + lr] =
                        __builtin_bit_cast(unsigned short, pb);
                }
    }
#undef STAGE
}

// ---------------- combine: branchless unrolled 8-way merge ----------------
__global__ __launch_bounds__(256)
void combine_kernel(float* __restrict__ Og, const unsigned short* __restrict__ accW,
                    const float* __restrict__ lmW)
{
    const int blk = (int)blockIdx.x;      // 0..4095
    const int rg = blk & 7;
    const int p  = (blk >> 3) & 31;
    const int h  = blk >> 8;

    const int m = p >> 2, n = m + 1;
    const int cid0 = 2 * m * (m + 1) + (p & 3) * n;
    const int lmB  = (h * CHUNKS_PER_H + cid0) * 128;
    const size_t obase = ((size_t)h * SS + (size_t)p * QB) * DD;
    const size_t ab0   = ((size_t)(h * ACCW_PER_H) + (cid0 - p)) * 8192;  // chunk ci=1

    const int row = rg * 16 + ((int)threadIdx.x >> 4);     // 0..127
    const int c4  = ((int)threadIdx.x & 15) * 4;           // 0..60

    // ---- per-row stats: 8-wide, clamped loads, padding weight-zeroed ----
    float mi[8], li[8];
#pragma unroll
    for (int i = 0; i < 8; ++i) {
        const int ic = (i < n) ? i : 0;
        mi[i] = lmW[lmB + ic * 128 + row];
        li[i] = lmW[LM_PLANE + lmB + ic * 128 + row];
    }
#pragma unroll
    for (int i = 0; i < 8; ++i) {
        if (i >= n) { mi[i] = -3.0e38f; li[i] = 0.f; }
    }
    const float mm = fmaxf(fmaxf(fmaxf(mi[0], mi[1]), fmaxf(mi[2], mi[3])),
                           fmaxf(fmaxf(mi[4], mi[5]), fmaxf(mi[6], mi[7])));
    float w[8];
    float den = 0.f;
#pragma unroll
    for (int i = 0; i < 8; ++i) {
        w[i] = fast_exp2(mi[i] - mm);     // exp2(-huge) = 0 for padding
        den += w[i] * li[i];
    }

    // ---- element merge: chunk0 (f32, in Og) + chunks 1..n-1 (bf16, accW) ----
    const size_t oi = obase + (size_t)row * DD + c4;
    fx4 val = *(const fx4*)(&Og[oi]);
    val[0] *= w[0]; val[1] *= w[0]; val[2] *= w[0]; val[3] *= w[0];

#pragma unroll
    for (int i = 1; i < 8; ++i) {
        const int ai = (i < n) ? (i - 1) : 0;              // clamped, always valid
        const usx4 ub = *(const usx4*)(&accW[ab0 + (size_t)ai * 8192 + row * 64 + c4]);
#pragma unroll
        for (int j = 0; j < 4; ++j) {
            const unsigned int bits = ((unsigned int)ub[j]) << 16;
            val[j] += w[i] * __builtin_bit_cast(float, bits);
        }
    }

    const float rinv = 1.f / den;
    val[0] *= rinv; val[1] *= rinv; val[2] *= rinv; val[3] *= rinv;
    *(fx4*)(&Og[oi]) = val;
}

extern "C" void kernel_launch(void* const* d_in, const int* in_sizes, int n_in,
                              void* d_out, int out_size, void* d_ws, size_t ws_size,
                              hipStream_t stream)
{
    (void)in_sizes; (void)n_in; (void)out_size; (void)ws_size;
    const float* q = (const float*)d_in[0];
    const float* k = (const float*)d_in[1];
    const float* v = (const float*)d_in[2];
    float*       o = (float*)d_out;

    char* ws = (char*)d_ws;
    char*           Kimg = ws;                                        // 8 MB
    char*           Vimg = ws + ((size_t)1 << 23);                    // 8 MB
    unsigned short* accW = (unsigned short*)(ws + ((size_t)2 << 23)); // 29.4 MB bf16 partials
    float*          lmW  = (float*)(ws + ((size_t)2 << 23) + 29360128); // 2.4 MB

    hipLaunchKernelGGL(prep_kernel,    dim3(NH * NKV),          dim3(256), 0, stream, k, v, Kimg, Vimg);
    hipLaunchKernelGGL(attn_fwd,       dim3(NH * CHUNKS_PER_H), dim3(256), 0, stream, q, Kimg, Vimg, o, accW, lmW);
    hipLaunchKernelGGL(combine_kernel, dim3(4096),              dim3(256), 0, stream, o, accW, lmW);
}

// Round 14
// 83.990 us; speedup vs baseline: 2.8773x; 1.0349x over previous
//
#include <hip/hip_runtime.h>

#define SS 4096
#define DD 64
#define NH 16
#define QB 128
#define NQB (SS / QB)      // 32
#define KVT 64
#define NKV (SS / KVT)     // 64
#define TILE_BYTES 8192    // 64 x 64 bf16

// chunking: q-block p has W=2p+2 tiles, split into n=(p>>2)+1 balanced chunks
// (target ~8 tiles). 144 chunks/head, 2304 blocks total.
#define CHUNKS_PER_H 144
#define ACCW_PER_H   112   // chunks with ci>=1
#define LM_PLANE     (16 * CHUNKS_PER_H * 128)   // 294912

typedef float  fx4    __attribute__((ext_vector_type(4)));
typedef __bf16 bf16x8 __attribute__((ext_vector_type(8)));
typedef short  sx4    __attribute__((ext_vector_type(4)));
typedef unsigned short usx4 __attribute__((ext_vector_type(4)));

typedef __attribute__((address_space(1))) const unsigned int GU32;
typedef __attribute__((address_space(3))) unsigned int       LU32;

__device__ __forceinline__ void gload16(const void* g, void* l) {
    __builtin_amdgcn_global_load_lds((GU32*)g, (LU32*)l, 16, 0, 0);
}

__device__ __forceinline__ float fast_exp2(float x) {
    return __builtin_amdgcn_exp2f(x);   // v_exp_f32: 2^x
}

// ---------------- pre-pass: f32 K/V -> bf16 swizzled tile images ----------------
__global__ __launch_bounds__(256)
void prep_kernel(const float* __restrict__ Kg, const float* __restrict__ Vg,
                 char* __restrict__ Kimg, char* __restrict__ Vimg)
{
    __shared__ __bf16 lv[64][72];
    const int tid = threadIdx.x;
    const int h = (int)blockIdx.x >> 6;
    const int t = (int)blockIdx.x & 63;
    const int r = tid >> 2;                       // 0..63
    const size_t rowbase = ((size_t)h * SS + (size_t)t * KVT) * DD;

    // ---- K (swizzled 16B chunks) ----
    {
        char* kdst = Kimg + (size_t)(h * NKV + t) * TILE_BYTES;
        const float* src = Kg + rowbase + (size_t)r * DD;
#pragma unroll
        for (int cc = 0; cc < 2; ++cc) {
            const int c = (tid & 3) * 2 + cc;     // 0..7
            fx4 f0 = *(const fx4*)(src + c * 8);
            fx4 f1 = *(const fx4*)(src + c * 8 + 4);
            bf16x8 b;
#pragma unroll
            for (int j = 0; j < 4; ++j) { b[j] = (__bf16)f0[j]; b[4 + j] = (__bf16)f1[j]; }
            *(bf16x8*)(kdst + r * 128 + ((c ^ (r & 7)) << 4)) = b;
        }
    }

    // ---- V: load tile to LDS (row-major), then write transposed + swizzled ----
    {
        const float* src = Vg + rowbase + (size_t)r * DD + (tid & 3) * 16;
#pragma unroll
        for (int qq = 0; qq < 4; ++qq) {
            fx4 f = *(const fx4*)(src + qq * 4);
#pragma unroll
            for (int j = 0; j < 4; ++j) lv[r][(tid & 3) * 16 + qq * 4 + j] = (__bf16)f[j];
        }
    }
    __syncthreads();
    {
        char* vdst = Vimg + (size_t)(h * NKV + t) * TILE_BYTES;
        const int d = r;                          // VT row
#pragma unroll
        for (int cc = 0; cc < 2; ++cc) {
            const int c = (tid & 3) * 2 + cc;     // k-chunk 0..7
            bf16x8 b;
#pragma unroll
            for (int j = 0; j < 8; ++j) b[j] = lv[c * 8 + j][d];
            *(bf16x8*)(vdst + d * 128 + ((c ^ (d & 7)) << 4)) = b;
        }
    }
}

// ---------------- main kernel: 4 waves x 32 q-rows, 2-buffer, XCD-local ----------------
// XCD-aware decode: xcd = b&7 (round-robin dispatch), slot = b>>3;
//   h = xcd + 8*(slot&1), cid = 143 - (slot>>1)  -> each XCD serves exactly
//   2 heads (2 MB of K/V image, fits 4 MB XCD-L2); big chunks dispatch first.
// chunk ci: tiles [ci*W/n, (ci+1)*W/n), W = 2p+2.
// ci==0 -> raw f32 acc to Og; ci>=1 -> bf16 acc to accW. l/m per row to lmW.
__global__ __launch_bounds__(256, 4)
void attn_fwd(const float* __restrict__ Qg, const char* __restrict__ Kimg,
              const char* __restrict__ Vimg, float* __restrict__ Og,
              unsigned short* __restrict__ accW, float* __restrict__ lmW)
{
    __shared__ __align__(16) char lK[2][TILE_BYTES];
    __shared__ __align__(16) char lV[2][TILE_BYTES];   // 32 KB total

    const int tid  = threadIdx.x;
    const int wid  = tid >> 6;                    // 0..3
    const int lane = tid & 63;
    const int lr   = lane & 15;
    const int g    = lane >> 4;

    // ---- XCD-aware chunk decode (all scalar) ----
    const int b    = (int)blockIdx.x;             // 0..2303
    const int xcd  = b & 7;
    const int slot = b >> 3;                      // 0..287
    const int h    = xcd + ((slot & 1) << 3);
    int r_ = (CHUNKS_PER_H - 1) - (slot >> 1);    // logical cid, big-first
    const int cid = r_;
    int m = 0;
#pragma unroll
    for (int i = 0; i < 7; ++i) {                 // group m starts at 2m(m+1), width 4(m+1)
        if (r_ >= 4 * (i + 1)) { r_ -= 4 * (i + 1); m = i + 1; }
    }
    int p4 = 0;
#pragma unroll
    for (int i = 0; i < 3; ++i) {
        if (r_ >= m + 1) { r_ -= (m + 1); ++p4; }
    }
    const int p  = 4 * m + p4;
    const int ci = r_;
    const int n  = m + 1;
    const int W  = 2 * p + 2;
    const int t0 = (ci * W) / n;
    const int t1 = ((ci + 1) * W) / n;

    const int q0 = p * QB + wid * 32;             // wave owns 32 q rows (2 subtiles)

    const float* Qh = Qg + (size_t)h * SS * DD;
    float*       Oh = Og + (size_t)h * SS * DD;
    const char*  Kh = Kimg + (size_t)(h * NKV) * TILE_BYTES;
    const char*  Vh = Vimg + (size_t)(h * NKV) * TILE_BYTES;

    const float QSCALE = 0.125f * 1.44269504088896f;   // 1/sqrt(64) * log2(e)

    // Q fragments (held all kernel)
    bf16x8 qa[2][2];
#pragma unroll
    for (int u = 0; u < 2; ++u) {
        const int qrow = q0 + 16 * u + lr;
#pragma unroll
        for (int h2 = 0; h2 < 2; ++h2) {
            const float* src = Qh + (size_t)qrow * DD + h2 * 32 + g * 8;
            fx4 f0 = *(const fx4*)(src);
            fx4 f1 = *(const fx4*)(src + 4);
            bf16x8 tq;
#pragma unroll
            for (int jj = 0; jj < 4; ++jj) {
                tq[jj]     = (__bf16)(f0[jj] * QSCALE);
                tq[jj + 4] = (__bf16)(f1[jj] * QSCALE);
            }
            qa[u][h2] = tq;
        }
    }

    fx4 acc[2][4];
#pragma unroll
    for (int u = 0; u < 2; ++u)
#pragma unroll
        for (int d0 = 0; d0 < 4; ++d0) acc[u][d0] = (fx4){0.f, 0.f, 0.f, 0.f};
    float m_run = -1e30f;           // wave-uniform running max (log2 units)
    float l_run[2] = {0.f, 0.f};    // lane-local partial row sums

    // staging: waves 0,1 -> K tile halves; waves 2,3 -> V tile halves (4KB/wave)
#define STAGE(buf, tt)                                                          \
    do {                                                                        \
        const char* img_ = (wid < 2) ? Kh : Vh;                                 \
        char* dst_ = ((wid < 2) ? &lK[buf][0] : &lV[buf][0]) + (wid & 1) * 4096;\
        const char* src_ = img_ + (size_t)(tt) * TILE_BYTES + (wid & 1) * 4096  \
                           + lane * 16;                                         \
        gload16(src_,        dst_);                                             \
        gload16(src_ + 1024, dst_ + 1024);                                      \
        gload16(src_ + 2048, dst_ + 2048);                                      \
        gload16(src_ + 3072, dst_ + 3072);                                      \
    } while (0)

    STAGE(0, t0);
    __syncthreads();

    int cur = 0;
    for (int t = t0; t < t1; ++t) {
        if (t + 1 < t1) STAGE(cur ^ 1, t + 1);   // prefetch next tile

        // ---- QK^T (swapped: A=K tile rows, B=Q) ----
        float s[2][4][4];
        __builtin_amdgcn_s_setprio(1);
#pragma unroll
        for (int ks = 0; ks < 4; ++ks) {
            const int row = ks * 16 + lr;
            const char* base = &lK[cur][row * 128];
            const bf16x8 ka0 = *(const bf16x8*)(base + (((g    ) ^ (row & 7)) << 4));
            const bf16x8 ka1 = *(const bf16x8*)(base + (((g ^ 4) ^ (row & 7)) << 4));
#pragma unroll
            for (int u = 0; u < 2; ++u) {
                fx4 st = (fx4){0.f, 0.f, 0.f, 0.f};
                st = __builtin_amdgcn_mfma_f32_16x16x32_bf16(ka0, qa[u][0], st, 0, 0, 0);
                st = __builtin_amdgcn_mfma_f32_16x16x32_bf16(ka1, qa[u][1], st, 0, 0, 0);
#pragma unroll
                for (int r = 0; r < 4; ++r) s[u][ks][r] = st[r];
            }
        }
        __builtin_amdgcn_s_setprio(0);

        // ---- causal mask (tile crosses diagonal iff t >= 2p) ----
        if (t >= 2 * p) {
            const int kv0 = t * KVT;
#pragma unroll
            for (int u = 0; u < 2; ++u) {
                const int qrow = q0 + 16 * u + lr;
#pragma unroll
                for (int ks = 0; ks < 4; ++ks)
#pragma unroll
                    for (int r = 0; r < 4; ++r) {
                        const int kvi = kv0 + ks * 16 + 4 * g + r;
                        if (kvi > qrow) s[u][ks][r] = -1e30f;
                    }
            }
        }

        // ---- softmax: shuffle-free check, rare wave-uniform rescale ----
        float m4[2][4];
#pragma unroll
        for (int u = 0; u < 2; ++u)
#pragma unroll
            for (int ks = 0; ks < 4; ++ks)
                m4[u][ks] = fmaxf(fmaxf(s[u][ks][0], s[u][ks][1]),
                                  fmaxf(s[u][ks][2], s[u][ks][3]));
        const float tm = fmaxf(
            fmaxf(fmaxf(m4[0][0], m4[0][1]), fmaxf(m4[0][2], m4[0][3])),
            fmaxf(fmaxf(m4[1][0], m4[1][1]), fmaxf(m4[1][2], m4[1][3])));

        if (__any(tm > m_run + 8.0f)) {           // rare after first tile
            float wm = tm;
            wm = fmaxf(wm, __shfl_xor(wm, 1));
            wm = fmaxf(wm, __shfl_xor(wm, 2));
            wm = fmaxf(wm, __shfl_xor(wm, 4));
            wm = fmaxf(wm, __shfl_xor(wm, 8));
            wm = fmaxf(wm, __shfl_xor(wm, 16));
            wm = fmaxf(wm, __shfl_xor(wm, 32));   // wave max, uniform
            const float alpha = fast_exp2(m_run - wm);
            m_run = wm;
            l_run[0] *= alpha; l_run[1] *= alpha;
#pragma unroll
            for (int u = 0; u < 2; ++u)
#pragma unroll
                for (int d0 = 0; d0 < 4; ++d0) {
                    fx4 a = acc[u][d0];
                    a[0] *= alpha; a[1] *= alpha; a[2] *= alpha; a[3] *= alpha;
                    acc[u][d0] = a;
                }
        }

        sx4 pa[2][4];
#pragma unroll
        for (int u = 0; u < 2; ++u) {
#pragma unroll
            for (int ks = 0; ks < 4; ++ks)
#pragma unroll
                for (int r = 0; r < 4; ++r)
                    s[u][ks][r] = fast_exp2(s[u][ks][r] - m_run);   // in-place P
            const float u0 = (s[u][0][0] + s[u][0][1]) + (s[u][0][2] + s[u][0][3]);
            const float u1 = (s[u][1][0] + s[u][1][1]) + (s[u][1][2] + s[u][1][3]);
            const float u2 = (s[u][2][0] + s[u][2][1]) + (s[u][2][2] + s[u][2][3]);
            const float u3 = (s[u][3][0] + s[u][3][1]) + (s[u][3][2] + s[u][3][3]);
            l_run[u] += (u0 + u1) + (u2 + u3);
#pragma unroll
            for (int ks = 0; ks < 4; ++ks) {
                sx4 t4;
#pragma unroll
                for (int jj = 0; jj < 4; ++jj) {
                    const __bf16 pb = (__bf16)s[u][ks][jj];
                    t4[jj] = __builtin_bit_cast(short, pb);
                }
                pa[u][ks] = t4;
            }
        }

        // ---- PV: P fragments already in MFMA A-layout; V^T read swizzled ----
        __builtin_amdgcn_s_setprio(1);
#pragma unroll
        for (int ks = 0; ks < 4; ++ks) {
            const int s0 = ks * 2 + (g >> 1);     // k-chunk slot
#pragma unroll
            for (int d0 = 0; d0 < 4; ++d0) {
                const int row = d0 * 16 + lr;
                const sx4 vb = *(const sx4*)(&lV[cur][row * 128 +
                                ((s0 ^ (row & 7)) << 4) + (g & 1) * 8]);
                acc[0][d0] = __builtin_amdgcn_mfma_f32_16x16x16bf16_1k(pa[0][ks], vb, acc[0][d0], 0, 0, 0);
                acc[1][d0] = __builtin_amdgcn_mfma_f32_16x16x16bf16_1k(pa[1][ks], vb, acc[1][d0], 0, 0, 0);
            }
        }
        __builtin_amdgcn_s_setprio(0);

        if (t + 1 < t1) __syncthreads();
        cur ^= 1;
    }

    // ---- epilogue: reduce l across g, write partial + lm ----
    float ls0 = l_run[0];
    ls0 += __shfl_xor(ls0, 16);
    ls0 += __shfl_xor(ls0, 32);
    float ls1 = l_run[1];
    ls1 += __shfl_xor(ls1, 16);
    ls1 += __shfl_xor(ls1, 32);

    const int rowb = (h * CHUNKS_PER_H + cid) * 128 + wid * 32 + lr;
    if (lane < 16) {
        lmW[rowb]                  = m_run;
        lmW[rowb + 16]             = m_run;
        lmW[LM_PLANE + rowb]       = ls0;
        lmW[LM_PLANE + rowb + 16]  = ls1;
    }

    if (ci == 0) {                   // raw f32 acc -> Og
#pragma unroll
        for (int u = 0; u < 2; ++u)
#pragma unroll
            for (int d0 = 0; d0 < 4; ++d0)
#pragma unroll
                for (int r = 0; r < 4; ++r)
                    Oh[(size_t)(q0 + 16 * u + 4 * g + r) * DD + d0 * 16 + lr] = acc[u][d0][r];
    } else {                         // bf16 acc -> accW (dense idx = cid - p - 1)
        const size_t ab = ((size_t)(h * ACCW_PER_H) + (cid - p - 1)) * 8192
                        + (size_t)(wid * 32) * 64;
#pragma unroll
        for (int u = 0; u < 2; ++u)
#pragma unroll
            for (int d0 = 0; d0 < 4; ++d0)
#pragma unroll
                for (int r = 0; r < 4; ++r) {
                    const __bf16 pb = (__bf16)acc[u][d0][r];
                    accW[ab + (size_t)(16 * u + 4 * g + r) * 64 + d0 * 16 + lr] =
                        __builtin_bit_cast(unsigned short, pb);
                }
    }
#undef STAGE
}

// ---------------- combine: branchless unrolled 8-way merge ----------------
__global__ __launch_bounds__(256)
void combine_kernel(float* __restrict__ Og, const unsigned short* __restrict__ accW,
                    const float* __restrict__ lmW)
{
    const int blk = (int)blockIdx.x;      // 0..4095
    const int rg = blk & 7;
    const int p  = (blk >> 3) & 31;
    const int h  = blk >> 8;

    const int m = p >> 2, n = m + 1;
    const int cid0 = 2 * m * (m + 1) + (p & 3) * n;
    const int lmB  = (h * CHUNKS_PER_H + cid0) * 128;
    const size_t obase = ((size_t)h * SS + (size_t)p * QB) * DD;
    const size_t ab0   = ((size_t)(h * ACCW_PER_H) + (cid0 - p)) * 8192;  // chunk ci=1

    const int row = rg * 16 + ((int)threadIdx.x >> 4);     // 0..127
    const int c4  = ((int)threadIdx.x & 15) * 4;           // 0..60

    // ---- per-row stats: 8-wide, clamped loads, padding weight-zeroed ----
    float mi[8], li[8];
#pragma unroll
    for (int i = 0; i < 8; ++i) {
        const int ic = (i < n) ? i : 0;
        mi[i] = lmW[lmB + ic * 128 + row];
        li[i] = lmW[LM_PLANE + lmB + ic * 128 + row];
    }
#pragma unroll
    for (int i = 0; i < 8; ++i) {
        if (i >= n) { mi[i] = -3.0e38f; li[i] = 0.f; }
    }
    const float mm = fmaxf(fmaxf(fmaxf(mi[0], mi[1]), fmaxf(mi[2], mi[3])),
                           fmaxf(fmaxf(mi[4], mi[5]), fmaxf(mi[6], mi[7])));
    float w[8];
    float den = 0.f;
#pragma unroll
    for (int i = 0; i < 8; ++i) {
        w[i] = fast_exp2(mi[i] - mm);     // exp2(-huge) = 0 for padding
        den += w[i] * li[i];
    }

    // ---- element merge: chunk0 (f32, in Og) + chunks 1..n-1 (bf16, accW) ----
    const size_t oi = obase + (size_t)row * DD + c4;
    fx4 val = *(const fx4*)(&Og[oi]);
    val[0] *= w[0]; val[1] *= w[0]; val[2] *= w[0]; val[3] *= w[0];

#pragma unroll
    for (int i = 1; i < 8; ++i) {
        const int ai = (i < n) ? (i - 1) : 0;              // clamped, always valid
        const usx4 ub = *(const usx4*)(&accW[ab0 + (size_t)ai * 8192 + row * 64 + c4]);
#pragma unroll
        for (int j = 0; j < 4; ++j) {
            const unsigned int bits = ((unsigned int)ub[j]) << 16;
            val[j] += w[i] * __builtin_bit_cast(float, bits);
        }
    }

    const float rinv = 1.f / den;
    val[0] *= rinv; val[1] *= rinv; val[2] *= rinv; val[3] *= rinv;
    *(fx4*)(&Og[oi]) = val;
}

extern "C" void kernel_launch(void* const* d_in, const int* in_sizes, int n_in,
                              void* d_out, int out_size, void* d_ws, size_t ws_size,
                              hipStream_t stream)
{
    (void)in_sizes; (void)n_in; (void)out_size; (void)ws_size;
    const float* q = (const float*)d_in[0];
    const float* k = (const float*)d_in[1];
    const float* v = (const float*)d_in[2];
    float*       o = (float*)d_out;

    char* ws = (char*)d_ws;
    char*           Kimg = ws;                                        // 8 MB
    char*           Vimg = ws + ((size_t)1 << 23);                    // 8 MB
    unsigned short* accW = (unsigned short*)(ws + ((size_t)2 << 23)); // 29.4 MB bf16 partials
    float*          lmW  = (float*)(ws + ((size_t)2 << 23) + 29360128); // 2.4 MB

    hipLaunchKernelGGL(prep_kernel,    dim3(NH * NKV),          dim3(256), 0, stream, k, v, Kimg, Vimg);
    hipLaunchKernelGGL(attn_fwd,       dim3(NH * CHUNKS_PER_H), dim3(256), 0, stream, q, Kimg, Vimg, o, accW, lmW);
    hipLaunchKernelGGL(combine_kernel, dim3(4096),              dim3(256), 0, stream, o, accW, lmW);
}